// Round 1
// baseline (3037.748 us; speedup 1.0000x reference)
//
#include <hip/hip_runtime.h>

#define N_NODES 50000
#define N_EDGES 800000
#define N_GRAPHS 512
#define F_IN 96
#define HID 128

__global__ __launch_bounds__(256) void fill_f32(float* __restrict__ p, float v, int n) {
    int i = blockIdx.x * 256 + threadIdx.x;
    if (i < n) p[i] = v;
}

// deg[dst] += 1 per edge (deg pre-filled with 1.0 for the self-loop)
__global__ __launch_bounds__(256) void deg_count(const int* __restrict__ dst,
                                                 float* __restrict__ deg) {
    int e = blockIdx.x * 256 + threadIdx.x;
    if (e < N_EDGES) atomicAdd(&deg[dst[e]], 1.0f);
}

// deg -> 1/sqrt(deg), in place
__global__ __launch_bounds__(256) void make_dinv(float* __restrict__ deg) {
    int i = blockIdx.x * 256 + threadIdx.x;
    if (i < N_NODES) deg[i] = 1.0f / sqrtf(deg[i]);
}

// hp[row,:] = dinv[row] * (A[row,:] @ W)   A:[N_NODES,K]  W:[K,128]
// block = 256 threads, 32 rows/block; thread computes 4 rows x 4 cols.
template <int K>
__global__ __launch_bounds__(256) void gemm_scale(const float* __restrict__ A,
                                                  const float* __restrict__ W,
                                                  const float* __restrict__ dinv,
                                                  float* __restrict__ hp) {
    __shared__ float As[32 * K];
    __shared__ float Ws[32 * 128];
    const int tid = threadIdx.x;

    // stage A tile (32 rows x K), zero-pad beyond N_NODES
    {
        const long base = (long)blockIdx.x * (32 * K);
        const long limit = (long)N_NODES * K;
        for (int i = tid * 4; i < 32 * K; i += 1024) {
            long g = base + i;
            float4 v = make_float4(0.f, 0.f, 0.f, 0.f);
            if (g < limit) v = *(const float4*)(A + g);
            *(float4*)(As + i) = v;
        }
    }

    const int colg = tid & 31;   // cols colg*4 .. +3
    const int rowg = tid >> 5;   // 0..7
    const int r0 = rowg * 4;     // local row base

    float acc[4][4];
#pragma unroll
    for (int r = 0; r < 4; ++r)
#pragma unroll
        for (int c = 0; c < 4; ++c) acc[r][c] = 0.f;

    for (int kc = 0; kc < K; kc += 32) {
        __syncthreads();  // protect As (first iter) / previous Ws reads
        for (int i = tid * 4; i < 32 * 128; i += 1024)
            *(float4*)(Ws + i) = *(const float4*)(W + (long)kc * 128 + i);
        __syncthreads();

#pragma unroll
        for (int kk4 = 0; kk4 < 8; ++kk4) {
            float a[4][4];
#pragma unroll
            for (int r = 0; r < 4; ++r)
                *(float4*)&a[r][0] = *(const float4*)&As[(r0 + r) * K + kc + kk4 * 4];
#pragma unroll
            for (int j = 0; j < 4; ++j) {
                float wv[4];
                *(float4*)wv = *(const float4*)&Ws[(kk4 * 4 + j) * 128 + colg * 4];
#pragma unroll
                for (int r = 0; r < 4; ++r) {
#pragma unroll
                    for (int c = 0; c < 4; ++c) acc[r][c] += a[r][j] * wv[c];
                }
            }
        }
    }

    const int row0 = blockIdx.x * 32;
#pragma unroll
    for (int r = 0; r < 4; ++r) {
        int row = row0 + r0 + r;
        if (row < N_NODES) {
            float s = dinv[row];
            float4 o = make_float4(s * acc[r][0], s * acc[r][1], s * acc[r][2], s * acc[r][3]);
            *(float4*)(hp + (long)row * 128 + colg * 4) = o;
        }
    }
}

// acc[dst,:] += hp[src,:]  — 32 lanes per edge, float4 per lane
__global__ __launch_bounds__(256) void scatter_edges(const float* __restrict__ hp,
                                                     const int* __restrict__ src,
                                                     const int* __restrict__ dst,
                                                     float* __restrict__ acc) {
    long gid = (long)blockIdx.x * 256 + threadIdx.x;
    int e = (int)(gid >> 5);
    if (e >= N_EDGES) return;
    int c = ((int)gid & 31) * 4;
    int s = src[e];
    int d = dst[e];
    float4 v = *(const float4*)(hp + (long)s * 128 + c);
    float* o = acc + (long)d * 128 + c;
    atomicAdd(o + 0, v.x);
    atomicAdd(o + 1, v.y);
    atomicAdd(o + 2, v.z);
    atomicAdd(o + 3, v.w);
}

// hout = relu(dinv*(acc+hp) + b)
__global__ __launch_bounds__(256) void finalize_layer(const float* __restrict__ hp,
                                                      const float* __restrict__ acc,
                                                      const float* __restrict__ dinv,
                                                      const float* __restrict__ b,
                                                      float* __restrict__ hout) {
    int i = blockIdx.x * 256 + threadIdx.x;  // over N_NODES*32 float4 groups
    if (i >= N_NODES * 32) return;
    int node = i >> 5;
    int c4 = (i & 31) * 4;
    float s = dinv[node];
    float4 a = *(const float4*)(acc + (long)i * 4);
    float4 p = *(const float4*)(hp + (long)i * 4);
    float4 bb = *(const float4*)(b + c4);
    float4 o;
    o.x = fmaxf(s * (a.x + p.x) + bb.x, 0.f);
    o.y = fmaxf(s * (a.y + p.y) + bb.y, 0.f);
    o.z = fmaxf(s * (a.z + p.z) + bb.z, 0.f);
    o.w = fmaxf(s * (a.w + p.w) + bb.w, 0.f);
    *(float4*)(hout + (long)i * 4) = o;
}

__global__ __launch_bounds__(256) void count_nodes(const int* __restrict__ batch,
                                                   float* __restrict__ cnt) {
    int i = blockIdx.x * 256 + threadIdx.x;
    if (i < N_NODES) atomicAdd(&cnt[batch[i]], 1.0f);
}

__global__ __launch_bounds__(256) void init_out(float* __restrict__ out,
                                                const float* __restrict__ blin) {
    int i = blockIdx.x * 256 + threadIdx.x;
    if (i < N_GRAPHS * 2) out[i] = blin[i & 1];
}

// out[g,:] += (h[node,:] @ Wlin) / max(cnt[g],1)  — one wave (64 lanes) per node
__global__ __launch_bounds__(256) void pool_out(const float* __restrict__ h,
                                                const int* __restrict__ batch,
                                                const float* __restrict__ cnt,
                                                const float* __restrict__ Wlin,
                                                float* __restrict__ out) {
    long gid = (long)blockIdx.x * 256 + threadIdx.x;
    int node = (int)(gid >> 6);
    int lane = threadIdx.x & 63;
    if (node >= N_NODES) return;
    const float* hr = h + (long)node * 128;
    float h0 = hr[lane], h1 = hr[lane + 64];
    float s0 = h0 * Wlin[lane * 2 + 0] + h1 * Wlin[(lane + 64) * 2 + 0];
    float s1 = h0 * Wlin[lane * 2 + 1] + h1 * Wlin[(lane + 64) * 2 + 1];
#pragma unroll
    for (int off = 32; off > 0; off >>= 1) {
        s0 += __shfl_down(s0, off);
        s1 += __shfl_down(s1, off);
    }
    if (lane == 0) {
        int g = batch[node];
        float invc = 1.0f / fmaxf(cnt[g], 1.0f);
        atomicAdd(&out[g * 2 + 0], s0 * invc);
        atomicAdd(&out[g * 2 + 1], s1 * invc);
    }
}

extern "C" void kernel_launch(void* const* d_in, const int* in_sizes, int n_in,
                              void* d_out, int out_size, void* d_ws, size_t ws_size,
                              hipStream_t stream) {
    const float* x    = (const float*)d_in[0];
    const int*   ei   = (const int*)d_in[1];
    const int*   batch= (const int*)d_in[2];
    // d_in[3] = num_graphs (scalar) — compile-time constant here
    const float* W1   = (const float*)d_in[4];
    const float* b1   = (const float*)d_in[5];
    const float* W2   = (const float*)d_in[6];
    const float* b2   = (const float*)d_in[7];
    const float* Wlin = (const float*)d_in[8];
    const float* blin = (const float*)d_in[9];
    float* out = (float*)d_out;

    const int* src = ei;            // edge_index[0,:]
    const int* dst = ei + N_EDGES;  // edge_index[1,:]

    char* ws = (char*)d_ws;
    const size_t NH_BYTES = (size_t)N_NODES * HID * sizeof(float);  // 25.6 MB
    float* deg = (float*)ws;                            // 50000 floats (becomes dinv)
    float* hp  = (float*)(ws + 200704);                 // N x 128
    float* acc = (float*)(ws + 200704 + NH_BYTES);      // N x 128
    float* h   = (float*)(ws + 200704 + 2 * NH_BYTES);  // N x 128
    float* cnt = (float*)(ws + 200704 + 3 * NH_BYTES);  // 512 floats

    const int NB_N   = (N_NODES + 255) / 256;           // 196
    const int NB_E   = (N_EDGES + 255) / 256;           // 3125
    const int NB_NH4 = (N_NODES * 32 + 255) / 256;      // 6250
    const int NB_NH  = (N_NODES * HID + 255) / 256;     // 25000
    const int NB_G   = (N_NODES + 31) / 32;             // 1563 gemm blocks
    const int NB_SC  = (N_EDGES * 32) / 256;            // 100000
    const int NB_PL  = (N_NODES * 64) / 256;            // 12500

    // degree + dinv
    fill_f32<<<NB_N, 256, 0, stream>>>(deg, 1.0f, N_NODES);
    deg_count<<<NB_E, 256, 0, stream>>>(dst, deg);
    make_dinv<<<NB_N, 256, 0, stream>>>(deg);

    // layer 1
    gemm_scale<F_IN><<<NB_G, 256, 0, stream>>>(x, W1, deg, hp);
    fill_f32<<<NB_NH, 256, 0, stream>>>(acc, 0.0f, N_NODES * HID);
    scatter_edges<<<NB_SC, 256, 0, stream>>>(hp, src, dst, acc);
    finalize_layer<<<NB_NH4, 256, 0, stream>>>(hp, acc, deg, b1, h);

    // layer 2
    gemm_scale<HID><<<NB_G, 256, 0, stream>>>(h, W2, deg, hp);
    fill_f32<<<NB_NH, 256, 0, stream>>>(acc, 0.0f, N_NODES * HID);
    scatter_edges<<<NB_SC, 256, 0, stream>>>(hp, src, dst, acc);
    finalize_layer<<<NB_NH4, 256, 0, stream>>>(hp, acc, deg, b2, h);

    // pooling + head
    fill_f32<<<2, 256, 0, stream>>>(cnt, 0.0f, N_GRAPHS);
    count_nodes<<<NB_N, 256, 0, stream>>>(batch, cnt);
    init_out<<<4, 256, 0, stream>>>(out, blin);
    pool_out<<<NB_PL, 256, 0, stream>>>(h, batch, cnt, Wlin, out);
}

// Round 2
// 500.990 us; speedup vs baseline: 6.0635x; 6.0635x over previous
//
#include <hip/hip_runtime.h>

#define N_NODES 50000
#define N_EDGES 800000
#define N_GRAPHS 512
#define F_IN 96
#define HID 128
#define NB_SCAN 196  // ceil(50000/256)

__global__ __launch_bounds__(256) void fill_f32(float* __restrict__ p, float v, int n) {
    int i = blockIdx.x * 256 + threadIdx.x;
    if (i < n) p[i] = v;
}

__global__ __launch_bounds__(256) void fill_i32(int* __restrict__ p, int v, int n) {
    int i = blockIdx.x * 256 + threadIdx.x;
    if (i < n) p[i] = v;
}

// cnt[dst]++ per edge
__global__ __launch_bounds__(256) void hist_dst(const int* __restrict__ dst,
                                                int* __restrict__ cnt) {
    int e = blockIdx.x * 256 + threadIdx.x;
    if (e < N_EDGES) atomicAdd(&cnt[dst[e]], 1);
}

// per-block exclusive scan of cnt -> rowstart; block totals -> bsums
__global__ __launch_bounds__(256) void scan_blocks(const int* __restrict__ cnt,
                                                   int* __restrict__ rowstart,
                                                   int* __restrict__ bsums) {
    __shared__ int s[256];
    int i = blockIdx.x * 256 + threadIdx.x;
    int v = (i < N_NODES) ? cnt[i] : 0;
    s[threadIdx.x] = v;
    __syncthreads();
#pragma unroll
    for (int off = 1; off < 256; off <<= 1) {
        int t = 0;
        if (threadIdx.x >= off) t = s[threadIdx.x - off];
        __syncthreads();
        if (threadIdx.x >= off) s[threadIdx.x] += t;
        __syncthreads();
    }
    if (i < N_NODES) rowstart[i] = s[threadIdx.x] - v;  // exclusive
    if (threadIdx.x == 255) bsums[blockIdx.x] = s[255];
}

// exclusive scan of bsums in place (single block, NB_SCAN <= 256)
__global__ __launch_bounds__(256) void scan_bsums(int* __restrict__ bsums) {
    __shared__ int s[256];
    int v = (threadIdx.x < NB_SCAN) ? bsums[threadIdx.x] : 0;
    s[threadIdx.x] = v;
    __syncthreads();
#pragma unroll
    for (int off = 1; off < 256; off <<= 1) {
        int t = 0;
        if (threadIdx.x >= off) t = s[threadIdx.x - off];
        __syncthreads();
        if (threadIdx.x >= off) s[threadIdx.x] += t;
        __syncthreads();
    }
    if (threadIdx.x < NB_SCAN) bsums[threadIdx.x] = s[threadIdx.x] - v;
}

// rowstart += scanned block offset; cursor = rowstart; dinv = rsqrt(cnt+1)
__global__ __launch_bounds__(256) void finish_scan(int* __restrict__ rowstart,
                                                   const int* __restrict__ bsums,
                                                   int* __restrict__ cursor,
                                                   const int* __restrict__ cnt,
                                                   float* __restrict__ dinv) {
    int i = blockIdx.x * 256 + threadIdx.x;
    if (i < N_NODES) {
        int rs = rowstart[i] + bsums[blockIdx.x];
        rowstart[i] = rs;
        cursor[i] = rs;
        dinv[i] = rsqrtf((float)cnt[i] + 1.0f);
    }
}

// esrc[pos] = src, bucketed by dst
__global__ __launch_bounds__(256) void scatter_ids(const int* __restrict__ src,
                                                   const int* __restrict__ dst,
                                                   int* __restrict__ cursor,
                                                   int* __restrict__ esrc) {
    int e = blockIdx.x * 256 + threadIdx.x;
    if (e < N_EDGES) {
        int pos = atomicAdd(&cursor[dst[e]], 1);
        esrc[pos] = src[e];
    }
}

// hp[row,:] = dinv[row] * (A[row,:] @ W)   A:[N_NODES,K]  W:[K,128]
template <int K>
__global__ __launch_bounds__(256) void gemm_scale(const float* __restrict__ A,
                                                  const float* __restrict__ W,
                                                  const float* __restrict__ dinv,
                                                  float* __restrict__ hp) {
    __shared__ float As[32 * K];
    __shared__ float Ws[32 * 128];
    const int tid = threadIdx.x;

    {
        const long base = (long)blockIdx.x * (32 * K);
        const long limit = (long)N_NODES * K;
        for (int i = tid * 4; i < 32 * K; i += 1024) {
            long g = base + i;
            float4 v = make_float4(0.f, 0.f, 0.f, 0.f);
            if (g < limit) v = *(const float4*)(A + g);
            *(float4*)(As + i) = v;
        }
    }

    const int colg = tid & 31;
    const int rowg = tid >> 5;
    const int r0 = rowg * 4;

    float acc[4][4];
#pragma unroll
    for (int r = 0; r < 4; ++r)
#pragma unroll
        for (int c = 0; c < 4; ++c) acc[r][c] = 0.f;

    for (int kc = 0; kc < K; kc += 32) {
        __syncthreads();
        for (int i = tid * 4; i < 32 * 128; i += 1024)
            *(float4*)(Ws + i) = *(const float4*)(W + (long)kc * 128 + i);
        __syncthreads();

#pragma unroll
        for (int kk4 = 0; kk4 < 8; ++kk4) {
            float a[4][4];
#pragma unroll
            for (int r = 0; r < 4; ++r)
                *(float4*)&a[r][0] = *(const float4*)&As[(r0 + r) * K + kc + kk4 * 4];
#pragma unroll
            for (int j = 0; j < 4; ++j) {
                float wv[4];
                *(float4*)wv = *(const float4*)&Ws[(kk4 * 4 + j) * 128 + colg * 4];
#pragma unroll
                for (int r = 0; r < 4; ++r) {
#pragma unroll
                    for (int c = 0; c < 4; ++c) acc[r][c] += a[r][j] * wv[c];
                }
            }
        }
    }

    const int row0 = blockIdx.x * 32;
#pragma unroll
    for (int r = 0; r < 4; ++r) {
        int row = row0 + r0 + r;
        if (row < N_NODES) {
            float s = dinv[row];
            float4 o = make_float4(s * acc[r][0], s * acc[r][1], s * acc[r][2], s * acc[r][3]);
            *(float4*)(hp + (long)row * 128 + colg * 4) = o;
        }
    }
}

// one wave per dst node: hout[d,:] = relu(dinv[d]*(sum_{src in CSR[d]} hp[src,:] + hp[d,:]) + b)
__global__ __launch_bounds__(256) void aggregate(const float* __restrict__ hp,
                                                 const int* __restrict__ esrc,
                                                 const int* __restrict__ rowstart,
                                                 const int* __restrict__ cnt,
                                                 const float* __restrict__ dinv,
                                                 const float* __restrict__ b,
                                                 float* __restrict__ hout) {
    int node = blockIdx.x * 4 + (threadIdx.x >> 6);
    if (node >= N_NODES) return;
    int lane = threadIdx.x & 63;
    int start = rowstart[node];
    int end = start + cnt[node];

    float ax = 0.f, ay = 0.f;
    int j = start;
    // unroll by 2 for a little ILP
    for (; j + 1 < end; j += 2) {
        int s0 = esrc[j], s1 = esrc[j + 1];
        float2 v0 = *(const float2*)(hp + (long)s0 * 128 + lane * 2);
        float2 v1 = *(const float2*)(hp + (long)s1 * 128 + lane * 2);
        ax += v0.x + v1.x;
        ay += v0.y + v1.y;
    }
    if (j < end) {
        int s0 = esrc[j];
        float2 v0 = *(const float2*)(hp + (long)s0 * 128 + lane * 2);
        ax += v0.x;
        ay += v0.y;
    }

    float2 self = *(const float2*)(hp + (long)node * 128 + lane * 2);
    float d = dinv[node];
    float2 bb = *(const float2*)(b + lane * 2);
    float2 o;
    o.x = fmaxf(d * (ax + self.x) + bb.x, 0.f);
    o.y = fmaxf(d * (ay + self.y) + bb.y, 0.f);
    *(float2*)(hout + (long)node * 128 + lane * 2) = o;
}

__global__ __launch_bounds__(256) void count_nodes(const int* __restrict__ batch,
                                                   float* __restrict__ gcnt) {
    int i = blockIdx.x * 256 + threadIdx.x;
    if (i < N_NODES) atomicAdd(&gcnt[batch[i]], 1.0f);
}

__global__ __launch_bounds__(256) void init_out(float* __restrict__ out,
                                                const float* __restrict__ blin) {
    int i = blockIdx.x * 256 + threadIdx.x;
    if (i < N_GRAPHS * 2) out[i] = blin[i & 1];
}

// out[g,:] += (h[node,:] @ Wlin) / max(cnt[g],1)  — one wave per node
__global__ __launch_bounds__(256) void pool_out(const float* __restrict__ h,
                                                const int* __restrict__ batch,
                                                const float* __restrict__ gcnt,
                                                const float* __restrict__ Wlin,
                                                float* __restrict__ out) {
    long gid = (long)blockIdx.x * 256 + threadIdx.x;
    int node = (int)(gid >> 6);
    int lane = threadIdx.x & 63;
    if (node >= N_NODES) return;
    const float* hr = h + (long)node * 128;
    float h0 = hr[lane], h1 = hr[lane + 64];
    float s0 = h0 * Wlin[lane * 2 + 0] + h1 * Wlin[(lane + 64) * 2 + 0];
    float s1 = h0 * Wlin[lane * 2 + 1] + h1 * Wlin[(lane + 64) * 2 + 1];
#pragma unroll
    for (int off = 32; off > 0; off >>= 1) {
        s0 += __shfl_down(s0, off);
        s1 += __shfl_down(s1, off);
    }
    if (lane == 0) {
        int g = batch[node];
        float invc = 1.0f / fmaxf(gcnt[g], 1.0f);
        atomicAdd(&out[g * 2 + 0], s0 * invc);
        atomicAdd(&out[g * 2 + 1], s1 * invc);
    }
}

extern "C" void kernel_launch(void* const* d_in, const int* in_sizes, int n_in,
                              void* d_out, int out_size, void* d_ws, size_t ws_size,
                              hipStream_t stream) {
    const float* x    = (const float*)d_in[0];
    const int*   ei   = (const int*)d_in[1];
    const int*   batch= (const int*)d_in[2];
    const float* W1   = (const float*)d_in[4];
    const float* b1   = (const float*)d_in[5];
    const float* W2   = (const float*)d_in[6];
    const float* b2   = (const float*)d_in[7];
    const float* Wlin = (const float*)d_in[8];
    const float* blin = (const float*)d_in[9];
    float* out = (float*)d_out;

    const int* src = ei;
    const int* dst = ei + N_EDGES;

    char* ws = (char*)d_ws;
    const size_t NH_BYTES = (size_t)N_NODES * HID * sizeof(float);  // 25.6 MB
    const size_t NODE_I   = 256 * 1024;                             // padded 50000*4

    float* dinv     = (float*)(ws);
    int*   cnt      = (int*)  (ws + 1 * NODE_I);
    int*   rowstart = (int*)  (ws + 2 * NODE_I);
    int*   cursor   = (int*)  (ws + 3 * NODE_I);
    int*   bsums    = (int*)  (ws + 4 * NODE_I);            // 4 KB used
    float* gcnt     = (float*)(ws + 4 * NODE_I + 8192);     // 2 KB used
    int*   esrc     = (int*)  (ws + 5 * NODE_I);            // 3.2 MB
    float* hp       = (float*)(ws + 5 * NODE_I + 4 * 1024 * 1024);
    float* h        = (float*)(ws + 5 * NODE_I + 4 * 1024 * 1024 + NH_BYTES);

    const int NB_N  = (N_NODES + 255) / 256;   // 196
    const int NB_E  = (N_EDGES + 255) / 256;   // 3125
    const int NB_G  = (N_NODES + 31) / 32;     // 1563
    const int NB_AG = (N_NODES + 3) / 4;       // 12500
    const int NB_PL = (N_NODES * 64) / 256;    // 12500

    // ---- counting sort of edges by dst (once, reused by both layers) ----
    fill_i32<<<NB_N, 256, 0, stream>>>(cnt, 0, N_NODES);
    hist_dst<<<NB_E, 256, 0, stream>>>(dst, cnt);
    scan_blocks<<<NB_SCAN, 256, 0, stream>>>(cnt, rowstart, bsums);
    scan_bsums<<<1, 256, 0, stream>>>(bsums);
    finish_scan<<<NB_SCAN, 256, 0, stream>>>(rowstart, bsums, cursor, cnt, dinv);
    scatter_ids<<<NB_E, 256, 0, stream>>>(src, dst, cursor, esrc);

    // ---- layer 1 ----
    gemm_scale<F_IN><<<NB_G, 256, 0, stream>>>(x, W1, dinv, hp);
    aggregate<<<NB_AG, 256, 0, stream>>>(hp, esrc, rowstart, cnt, dinv, b1, h);

    // ---- layer 2 ----
    gemm_scale<HID><<<NB_G, 256, 0, stream>>>(h, W2, dinv, hp);
    aggregate<<<NB_AG, 256, 0, stream>>>(hp, esrc, rowstart, cnt, dinv, b2, h);

    // ---- pooling + head ----
    fill_f32<<<2, 256, 0, stream>>>(gcnt, 0.0f, N_GRAPHS);
    count_nodes<<<NB_N, 256, 0, stream>>>(batch, gcnt);
    init_out<<<4, 256, 0, stream>>>(out, blin);
    pool_out<<<NB_PL, 256, 0, stream>>>(h, batch, gcnt, Wlin, out);
}

// Round 4
// 358.051 us; speedup vs baseline: 8.4841x; 1.3992x over previous
//
#include <hip/hip_runtime.h>

#define N_NODES 50000
#define N_EDGES 800000
#define N_GRAPHS 512
#define F_IN 96
#define HID 128
#define NB_SCAN 196  // ceil(50000/256)

__global__ __launch_bounds__(256) void fill_i32(int* __restrict__ p, int v, int n) {
    int i = blockIdx.x * 256 + threadIdx.x;
    if (i < n) p[i] = v;
}

// cnt[dst]++ per edge
__global__ __launch_bounds__(256) void hist_dst(const int* __restrict__ dst,
                                                int* __restrict__ cnt) {
    int e = blockIdx.x * 256 + threadIdx.x;
    if (e < N_EDGES) atomicAdd(&cnt[dst[e]], 1);
}

// per-block exclusive scan of cnt -> rowstart; block totals -> bsums
__global__ __launch_bounds__(256) void scan_blocks(const int* __restrict__ cnt,
                                                   int* __restrict__ rowstart,
                                                   int* __restrict__ bsums) {
    __shared__ int s[256];
    int i = blockIdx.x * 256 + threadIdx.x;
    int v = (i < N_NODES) ? cnt[i] : 0;
    s[threadIdx.x] = v;
    __syncthreads();
#pragma unroll
    for (int off = 1; off < 256; off <<= 1) {
        int t = 0;
        if (threadIdx.x >= off) t = s[threadIdx.x - off];
        __syncthreads();
        if (threadIdx.x >= off) s[threadIdx.x] += t;
        __syncthreads();
    }
    if (i < N_NODES) rowstart[i] = s[threadIdx.x] - v;  // exclusive
    if (threadIdx.x == 255) bsums[blockIdx.x] = s[255];
}

// exclusive scan of bsums in place (single block, NB_SCAN <= 256)
__global__ __launch_bounds__(256) void scan_bsums(int* __restrict__ bsums) {
    __shared__ int s[256];
    int v = (threadIdx.x < NB_SCAN) ? bsums[threadIdx.x] : 0;
    s[threadIdx.x] = v;
    __syncthreads();
#pragma unroll
    for (int off = 1; off < 256; off <<= 1) {
        int t = 0;
        if (threadIdx.x >= off) t = s[threadIdx.x - off];
        __syncthreads();
        if (threadIdx.x >= off) s[threadIdx.x] += t;
        __syncthreads();
    }
    if (threadIdx.x < NB_SCAN) bsums[threadIdx.x] = s[threadIdx.x] - v;
}

// rowstart += scanned block offset; cursor = rowstart; dinv = rsqrt(cnt+1)
__global__ __launch_bounds__(256) void finish_scan(int* __restrict__ rowstart,
                                                   const int* __restrict__ bsums,
                                                   int* __restrict__ cursor,
                                                   const int* __restrict__ cnt,
                                                   float* __restrict__ dinv) {
    int i = blockIdx.x * 256 + threadIdx.x;
    if (i < N_NODES) {
        int rs = rowstart[i] + bsums[blockIdx.x];
        rowstart[i] = rs;
        cursor[i] = rs;
        dinv[i] = rsqrtf((float)cnt[i] + 1.0f);
    }
}

// esrc[pos] = src, bucketed by dst
__global__ __launch_bounds__(256) void scatter_ids(const int* __restrict__ src,
                                                   const int* __restrict__ dst,
                                                   int* __restrict__ cursor,
                                                   int* __restrict__ esrc) {
    int e = blockIdx.x * 256 + threadIdx.x;
    if (e < N_EDGES) {
        int pos = atomicAdd(&cursor[dst[e]], 1);
        esrc[pos] = src[e];
    }
}

// hp[row,:] = dinv[row] * (A[row,:] @ W)   A:[N_NODES,K]  W:[K,128]
template <int K>
__global__ __launch_bounds__(256) void gemm_scale(const float* __restrict__ A,
                                                  const float* __restrict__ W,
                                                  const float* __restrict__ dinv,
                                                  float* __restrict__ hp) {
    __shared__ float As[32 * K];
    __shared__ float Ws[32 * 128];
    const int tid = threadIdx.x;

    {
        const long base = (long)blockIdx.x * (32 * K);
        const long limit = (long)N_NODES * K;
        for (int i = tid * 4; i < 32 * K; i += 1024) {
            long g = base + i;
            float4 v = make_float4(0.f, 0.f, 0.f, 0.f);
            if (g < limit) v = *(const float4*)(A + g);
            *(float4*)(As + i) = v;
        }
    }

    const int colg = tid & 31;
    const int rowg = tid >> 5;
    const int r0 = rowg * 4;

    float acc[4][4];
#pragma unroll
    for (int r = 0; r < 4; ++r)
#pragma unroll
        for (int c = 0; c < 4; ++c) acc[r][c] = 0.f;

    for (int kc = 0; kc < K; kc += 32) {
        __syncthreads();
        for (int i = tid * 4; i < 32 * 128; i += 1024)
            *(float4*)(Ws + i) = *(const float4*)(W + (long)kc * 128 + i);
        __syncthreads();

#pragma unroll
        for (int kk4 = 0; kk4 < 8; ++kk4) {
            float a[4][4];
#pragma unroll
            for (int r = 0; r < 4; ++r)
                *(float4*)&a[r][0] = *(const float4*)&As[(r0 + r) * K + kc + kk4 * 4];
#pragma unroll
            for (int j = 0; j < 4; ++j) {
                float wv[4];
                *(float4*)wv = *(const float4*)&Ws[(kk4 * 4 + j) * 128 + colg * 4];
#pragma unroll
                for (int r = 0; r < 4; ++r) {
#pragma unroll
                    for (int c = 0; c < 4; ++c) acc[r][c] += a[r][j] * wv[c];
                }
            }
        }
    }

    const int row0 = blockIdx.x * 32;
#pragma unroll
    for (int r = 0; r < 4; ++r) {
        int row = row0 + r0 + r;
        if (row < N_NODES) {
            float s = dinv[row];
            float4 o = make_float4(s * acc[r][0], s * acc[r][1], s * acc[r][2], s * acc[r][3]);
            *(float4*)(hp + (long)row * 128 + colg * 4) = o;
        }
    }
}

// one wave per dst node: hout[d,:] = relu(dinv[d]*(sum_{src in CSR[d]} hp[src,:] + hp[d,:]) + b)
__global__ __launch_bounds__(256) void aggregate(const float* __restrict__ hp,
                                                 const int* __restrict__ esrc,
                                                 const int* __restrict__ rowstart,
                                                 const int* __restrict__ cnt,
                                                 const float* __restrict__ dinv,
                                                 const float* __restrict__ b,
                                                 float* __restrict__ hout) {
    int node = blockIdx.x * 4 + (threadIdx.x >> 6);
    if (node >= N_NODES) return;
    int lane = threadIdx.x & 63;
    int start = rowstart[node];
    int end = start + cnt[node];

    float ax = 0.f, ay = 0.f;
    int j = start;
    for (; j + 1 < end; j += 2) {
        int s0 = esrc[j], s1 = esrc[j + 1];
        float2 v0 = *(const float2*)(hp + (long)s0 * 128 + lane * 2);
        float2 v1 = *(const float2*)(hp + (long)s1 * 128 + lane * 2);
        ax += v0.x + v1.x;
        ay += v0.y + v1.y;
    }
    if (j < end) {
        int s0 = esrc[j];
        float2 v0 = *(const float2*)(hp + (long)s0 * 128 + lane * 2);
        ax += v0.x;
        ay += v0.y;
    }

    float2 self = *(const float2*)(hp + (long)node * 128 + lane * 2);
    float d = dinv[node];
    float2 bb = *(const float2*)(b + lane * 2);
    float2 o;
    o.x = fmaxf(d * (ax + self.x) + bb.x, 0.f);
    o.y = fmaxf(d * (ay + self.y) + bb.y, 0.f);
    *(float2*)(hout + (long)node * 128 + lane * 2) = o;
}

// gstart[g] = first node index i with batch[i] >= g   (g in [0, N_GRAPHS])
__global__ __launch_bounds__(256) void graph_bounds(const int* __restrict__ batch,
                                                    int* __restrict__ gstart) {
    int g = blockIdx.x * 256 + threadIdx.x;
    if (g > N_GRAPHS) return;
    int lo = 0, hi = N_NODES;
    while (lo < hi) {
        int mid = (lo + hi) >> 1;
        if (batch[mid] < g) lo = mid + 1;
        else hi = mid;
    }
    gstart[g] = lo;
}

// one block (128 threads) per graph: out[g,:] = mean(h[gstart[g]:gstart[g+1],:]) @ Wlin + blin
__global__ __launch_bounds__(128) void pool_head(const float* __restrict__ h,
                                                 const int* __restrict__ gstart,
                                                 const float* __restrict__ Wlin,
                                                 const float* __restrict__ blin,
                                                 float* __restrict__ out) {
    int g = blockIdx.x;
    int c = threadIdx.x;  // column 0..127
    int s = gstart[g], e = gstart[g + 1];

    float sum = 0.f;
    int i = s;
#pragma unroll 4
    for (; i + 4 <= e; i += 4) {
        sum += h[(long)(i + 0) * 128 + c];
        sum += h[(long)(i + 1) * 128 + c];
        sum += h[(long)(i + 2) * 128 + c];
        sum += h[(long)(i + 3) * 128 + c];
    }
    for (; i < e; ++i) sum += h[(long)i * 128 + c];

    float inv = (e > s) ? 1.0f / (float)(e - s) : 1.0f;  // max(cnt,1)
    float m = sum * inv;

    __shared__ float red[128][2];
    red[c][0] = m * Wlin[c * 2 + 0];
    red[c][1] = m * Wlin[c * 2 + 1];
    __syncthreads();
#pragma unroll
    for (int off = 64; off > 0; off >>= 1) {
        if (c < off) {
            red[c][0] += red[c + off][0];
            red[c][1] += red[c + off][1];
        }
        __syncthreads();
    }
    if (c < 2) out[g * 2 + c] = red[0][c] + blin[c];
}

extern "C" void kernel_launch(void* const* d_in, const int* in_sizes, int n_in,
                              void* d_out, int out_size, void* d_ws, size_t ws_size,
                              hipStream_t stream) {
    const float* x    = (const float*)d_in[0];
    const int*   ei   = (const int*)d_in[1];
    const int*   batch= (const int*)d_in[2];
    const float* W1   = (const float*)d_in[4];
    const float* b1   = (const float*)d_in[5];
    const float* W2   = (const float*)d_in[6];
    const float* b2   = (const float*)d_in[7];
    const float* Wlin = (const float*)d_in[8];
    const float* blin = (const float*)d_in[9];
    float* out = (float*)d_out;

    const int* src = ei;
    const int* dst = ei + N_EDGES;

    char* ws = (char*)d_ws;
    const size_t NH_BYTES = (size_t)N_NODES * HID * sizeof(float);  // 25.6 MB
    const size_t NODE_I   = 256 * 1024;

    float* dinv     = (float*)(ws);
    int*   cnt      = (int*)  (ws + 1 * NODE_I);
    int*   rowstart = (int*)  (ws + 2 * NODE_I);
    int*   cursor   = (int*)  (ws + 3 * NODE_I);
    int*   bsums    = (int*)  (ws + 4 * NODE_I);           // 4 KB used
    int*   gstart   = (int*)  (ws + 4 * NODE_I + 8192);    // 513 ints
    int*   esrc     = (int*)  (ws + 5 * NODE_I);           // 3.2 MB
    float* hp       = (float*)(ws + 5 * NODE_I + 4 * 1024 * 1024);
    float* h        = (float*)(ws + 5 * NODE_I + 4 * 1024 * 1024 + NH_BYTES);

    const int NB_N  = (N_NODES + 255) / 256;   // 196
    const int NB_E  = (N_EDGES + 255) / 256;   // 3125
    const int NB_G  = (N_NODES + 31) / 32;     // 1563
    const int NB_AG = (N_NODES + 3) / 4;       // 12500

    // ---- counting sort of edges by dst (once, reused by both layers) ----
    fill_i32<<<NB_N, 256, 0, stream>>>(cnt, 0, N_NODES);
    hist_dst<<<NB_E, 256, 0, stream>>>(dst, cnt);
    scan_blocks<<<NB_SCAN, 256, 0, stream>>>(cnt, rowstart, bsums);
    scan_bsums<<<1, 256, 0, stream>>>(bsums);
    finish_scan<<<NB_SCAN, 256, 0, stream>>>(rowstart, bsums, cursor, cnt, dinv);
    scatter_ids<<<NB_E, 256, 0, stream>>>(src, dst, cursor, esrc);

    // ---- layer 1 ----
    gemm_scale<F_IN><<<NB_G, 256, 0, stream>>>(x, W1, dinv, hp);
    aggregate<<<NB_AG, 256, 0, stream>>>(hp, esrc, rowstart, cnt, dinv, b1, h);

    // ---- layer 2 ----
    gemm_scale<HID><<<NB_G, 256, 0, stream>>>(h, W2, dinv, hp);
    aggregate<<<NB_AG, 256, 0, stream>>>(hp, esrc, rowstart, cnt, dinv, b2, h);

    // ---- pooling + head (no atomics: batch is sorted -> contiguous ranges) ----
    graph_bounds<<<3, 256, 0, stream>>>(batch, gstart);
    pool_head<<<N_GRAPHS, 128, 0, stream>>>(h, gstart, Wlin, blin, out);
}

// Round 5
// 326.819 us; speedup vs baseline: 9.2949x; 1.0956x over previous
//
#include <hip/hip_runtime.h>

#define N_NODES 50000
#define N_PAD   50048   // 782 * 64, padded row count for MFMA tiles
#define N_EDGES 800000
#define N_GRAPHS 512
#define F_IN 96
#define HID 128
#define NB_SCAN 196  // ceil(50000/256)

typedef __bf16 bf16x8 __attribute__((ext_vector_type(8)));
typedef float  f32x4  __attribute__((ext_vector_type(4)));

__device__ __forceinline__ unsigned short f2bf(float f) {
    union { float f; unsigned u; } v; v.f = f;
    unsigned r = v.u + 0x7FFFu + ((v.u >> 16) & 1u);  // RNE
    return (unsigned short)(r >> 16);
}
__device__ __forceinline__ float bflo(unsigned u) {  // low bf16 of packed pair
    union { unsigned u; float f; } v; v.u = u << 16; return v.f;
}
__device__ __forceinline__ float bfhi(unsigned u) {  // high bf16 of packed pair
    union { unsigned u; float f; } v; v.u = u & 0xFFFF0000u; return v.f;
}

// ---------------- sort machinery (unchanged from R4) ----------------

__global__ __launch_bounds__(256) void fill_i32(int* __restrict__ p, int v, int n) {
    int i = blockIdx.x * 256 + threadIdx.x;
    if (i < n) p[i] = v;
}

__global__ __launch_bounds__(256) void hist_dst(const int* __restrict__ dst,
                                                int* __restrict__ cnt) {
    int e = blockIdx.x * 256 + threadIdx.x;
    if (e < N_EDGES) atomicAdd(&cnt[dst[e]], 1);
}

__global__ __launch_bounds__(256) void scan_blocks(const int* __restrict__ cnt,
                                                   int* __restrict__ rowstart,
                                                   int* __restrict__ bsums) {
    __shared__ int s[256];
    int i = blockIdx.x * 256 + threadIdx.x;
    int v = (i < N_NODES) ? cnt[i] : 0;
    s[threadIdx.x] = v;
    __syncthreads();
#pragma unroll
    for (int off = 1; off < 256; off <<= 1) {
        int t = 0;
        if (threadIdx.x >= off) t = s[threadIdx.x - off];
        __syncthreads();
        if (threadIdx.x >= off) s[threadIdx.x] += t;
        __syncthreads();
    }
    if (i < N_NODES) rowstart[i] = s[threadIdx.x] - v;
    if (threadIdx.x == 255) bsums[blockIdx.x] = s[255];
}

__global__ __launch_bounds__(256) void scan_bsums(int* __restrict__ bsums) {
    __shared__ int s[256];
    int v = (threadIdx.x < NB_SCAN) ? bsums[threadIdx.x] : 0;
    s[threadIdx.x] = v;
    __syncthreads();
#pragma unroll
    for (int off = 1; off < 256; off <<= 1) {
        int t = 0;
        if (threadIdx.x >= off) t = s[threadIdx.x - off];
        __syncthreads();
        if (threadIdx.x >= off) s[threadIdx.x] += t;
        __syncthreads();
    }
    if (threadIdx.x < NB_SCAN) bsums[threadIdx.x] = s[threadIdx.x] - v;
}

__global__ __launch_bounds__(256) void finish_scan(int* __restrict__ rowstart,
                                                   const int* __restrict__ bsums,
                                                   int* __restrict__ cursor,
                                                   const int* __restrict__ cnt,
                                                   float* __restrict__ dinv) {
    int i = blockIdx.x * 256 + threadIdx.x;
    if (i < N_NODES) {
        int rs = rowstart[i] + bsums[blockIdx.x];
        rowstart[i] = rs;
        cursor[i] = rs;
        dinv[i] = rsqrtf((float)cnt[i] + 1.0f);
    }
}

__global__ __launch_bounds__(256) void scatter_ids(const int* __restrict__ src,
                                                   const int* __restrict__ dst,
                                                   int* __restrict__ cursor,
                                                   int* __restrict__ esrc) {
    int e = blockIdx.x * 256 + threadIdx.x;
    if (e < N_EDGES) {
        int pos = atomicAdd(&cursor[dst[e]], 1);
        esrc[pos] = src[e];
    }
}

// ---------------- bf16 conversion / W pre-swizzle ----------------

// x f32 -> xb bf16, 8 elements per thread
__global__ __launch_bounds__(256) void convert_x(const float* __restrict__ x,
                                                 unsigned short* __restrict__ xb) {
    int i = blockIdx.x * 256 + threadIdx.x;
    if (i >= N_NODES * F_IN / 8) return;
    const float4* p = (const float4*)(x + (long)i * 8);
    float4 a = p[0], b = p[1];
    uint4 o;
    o.x = (unsigned)f2bf(a.x) | ((unsigned)f2bf(a.y) << 16);
    o.y = (unsigned)f2bf(a.z) | ((unsigned)f2bf(a.w) << 16);
    o.z = (unsigned)f2bf(b.x) | ((unsigned)f2bf(b.y) << 16);
    o.w = (unsigned)f2bf(b.z) | ((unsigned)f2bf(b.w) << 16);
    *(uint4*)(xb + (long)i * 8) = o;
}

// W f32 [K x 128] -> Wf bf16 in B-fragment order:
// frag idx = (t*KS + s)*64 + lane; element j: B[k = s*32 + (lane>>4)*8 + j][n = t*16 + (lane&15)]
template <int K>
__global__ __launch_bounds__(256) void prep_W(const float* __restrict__ W,
                                              unsigned short* __restrict__ Wf) {
    const int KS = K / 32;
    int idx = blockIdx.x * 256 + threadIdx.x;
    if (idx >= 8 * KS * 64) return;
    int t = idx / (KS * 64);
    int rem = idx % (KS * 64);
    int s = rem / 64;
    int l = rem & 63;
    int n = t * 16 + (l & 15);
    int k0 = s * 32 + (l >> 4) * 8;
    unsigned short v[8];
#pragma unroll
    for (int j = 0; j < 8; ++j) v[j] = f2bf(W[(long)(k0 + j) * 128 + n]);
    uint4 o;
    o.x = (unsigned)v[0] | ((unsigned)v[1] << 16);
    o.y = (unsigned)v[2] | ((unsigned)v[3] << 16);
    o.z = (unsigned)v[4] | ((unsigned)v[5] << 16);
    o.w = (unsigned)v[6] | ((unsigned)v[7] << 16);
    *(uint4*)(Wf + (long)idx * 8) = o;
}

// ---------------- MFMA GEMM:  hp[row,:] = bf16( dinv[row] * (A[row,:] @ W) ) ----------------
// block = 256 (4 waves); wave w owns rows r0 = blk*64 + w*16, all 128 cols (8 16x16 tiles).
// No LDS, no barriers: A-frags direct from bf16 global; B-frags from pre-swizzled L2-hot Wf.
template <int K>
__global__ __launch_bounds__(256) void gemm_mfma(const unsigned short* __restrict__ A,
                                                 const unsigned short* __restrict__ Wf,
                                                 const float* __restrict__ dinv,
                                                 unsigned short* __restrict__ hp) {
    const int KS = K / 32;
    const int wave = threadIdx.x >> 6;
    const int lane = threadIdx.x & 63;
    const int r0 = blockIdx.x * 64 + wave * 16;

    f32x4 acc[8];
#pragma unroll
    for (int t = 0; t < 8; ++t) acc[t] = (f32x4){0.f, 0.f, 0.f, 0.f};

    const int arow = r0 + (lane & 15);
    const int kq = (lane >> 4) * 8;

    for (int s = 0; s < KS; ++s) {
        union { uint4 u; bf16x8 b; } af;
        af.u = *(const uint4*)(A + (long)arow * K + s * 32 + kq);
#pragma unroll
        for (int t = 0; t < 8; ++t) {
            union { uint4 u; bf16x8 b; } bfr;
            bfr.u = *(const uint4*)(Wf + ((long)(t * KS + s) * 64 + lane) * 8);
            acc[t] = __builtin_amdgcn_mfma_f32_16x16x32_bf16(af.b, bfr.b, acc[t], 0, 0, 0);
        }
    }

    const int q = lane >> 4;
    float dv[4];
#pragma unroll
    for (int r = 0; r < 4; ++r) {
        int row = r0 + q * 4 + r;
        dv[r] = dinv[row < N_NODES ? row : 0];
    }
#pragma unroll
    for (int t = 0; t < 8; ++t) {
        int col = t * 16 + (lane & 15);
#pragma unroll
        for (int r = 0; r < 4; ++r) {
            int row = r0 + q * 4 + r;
            if (row < N_NODES)
                hp[(long)row * 128 + col] = f2bf(acc[t][r] * dv[r]);
        }
    }
}

// ---------------- aggregate (bf16 gather, f32 accumulate, bf16 out) ----------------
// one wave per dst node; lane owns cols {2*lane, 2*lane+1} (one packed uint)
__global__ __launch_bounds__(256) void aggregate_bf16(const unsigned* __restrict__ hp,
                                                      const int* __restrict__ esrc,
                                                      const int* __restrict__ rowstart,
                                                      const int* __restrict__ cnt,
                                                      const float* __restrict__ dinv,
                                                      const float* __restrict__ b,
                                                      unsigned* __restrict__ hout) {
    int node = blockIdx.x * 4 + (threadIdx.x >> 6);
    if (node >= N_NODES) return;
    int lane = threadIdx.x & 63;
    int start = rowstart[node];
    int end = start + cnt[node];

    float ax = 0.f, ay = 0.f;
    int j = start;
    for (; j + 3 < end; j += 4) {
        int s0 = esrc[j], s1 = esrc[j + 1], s2 = esrc[j + 2], s3 = esrc[j + 3];
        unsigned u0 = hp[(long)s0 * 64 + lane];
        unsigned u1 = hp[(long)s1 * 64 + lane];
        unsigned u2 = hp[(long)s2 * 64 + lane];
        unsigned u3 = hp[(long)s3 * 64 + lane];
        ax += bflo(u0) + bflo(u1) + bflo(u2) + bflo(u3);
        ay += bfhi(u0) + bfhi(u1) + bfhi(u2) + bfhi(u3);
    }
    for (; j < end; ++j) {
        unsigned u = hp[(long)esrc[j] * 64 + lane];
        ax += bflo(u);
        ay += bfhi(u);
    }

    unsigned us = hp[(long)node * 64 + lane];
    float d = dinv[node];
    float2 bb = *(const float2*)(b + lane * 2);
    float ox = fmaxf(d * (ax + bflo(us)) + bb.x, 0.f);
    float oy = fmaxf(d * (ay + bfhi(us)) + bb.y, 0.f);
    hout[(long)node * 64 + lane] = (unsigned)f2bf(ox) | ((unsigned)f2bf(oy) << 16);
}

// ---------------- pooling + head ----------------

__global__ __launch_bounds__(256) void graph_bounds(const int* __restrict__ batch,
                                                    int* __restrict__ gstart) {
    int g = blockIdx.x * 256 + threadIdx.x;
    if (g > N_GRAPHS) return;
    int lo = 0, hi = N_NODES;
    while (lo < hi) {
        int mid = (lo + hi) >> 1;
        if (batch[mid] < g) lo = mid + 1;
        else hi = mid;
    }
    gstart[g] = lo;
}

__global__ __launch_bounds__(128) void pool_head(const unsigned short* __restrict__ h,
                                                 const int* __restrict__ gstart,
                                                 const float* __restrict__ Wlin,
                                                 const float* __restrict__ blin,
                                                 float* __restrict__ out) {
    int g = blockIdx.x;
    int c = threadIdx.x;  // column 0..127
    int s = gstart[g], e = gstart[g + 1];

    float sum = 0.f;
    for (int i = s; i < e; ++i) {
        union { unsigned u; float f; } v;
        v.u = (unsigned)h[(long)i * 128 + c] << 16;
        sum += v.f;
    }
    float inv = (e > s) ? 1.0f / (float)(e - s) : 1.0f;
    float m = sum * inv;

    __shared__ float red[128][2];
    red[c][0] = m * Wlin[c * 2 + 0];
    red[c][1] = m * Wlin[c * 2 + 1];
    __syncthreads();
#pragma unroll
    for (int off = 64; off > 0; off >>= 1) {
        if (c < off) {
            red[c][0] += red[c + off][0];
            red[c][1] += red[c + off][1];
        }
        __syncthreads();
    }
    if (c < 2) out[g * 2 + c] = red[0][c] + blin[c];
}

extern "C" void kernel_launch(void* const* d_in, const int* in_sizes, int n_in,
                              void* d_out, int out_size, void* d_ws, size_t ws_size,
                              hipStream_t stream) {
    const float* x    = (const float*)d_in[0];
    const int*   ei   = (const int*)d_in[1];
    const int*   batch= (const int*)d_in[2];
    const float* W1   = (const float*)d_in[4];
    const float* b1   = (const float*)d_in[5];
    const float* W2   = (const float*)d_in[6];
    const float* b2   = (const float*)d_in[7];
    const float* Wlin = (const float*)d_in[8];
    const float* blin = (const float*)d_in[9];
    float* out = (float*)d_out;

    const int* src = ei;
    const int* dst = ei + N_EDGES;

    char* ws = (char*)d_ws;
    const size_t NODE_I = 256 * 1024;
    const size_t MB = 1024 * 1024;

    float* dinv     = (float*)(ws);
    int*   cnt      = (int*)  (ws + 1 * NODE_I);
    int*   rowstart = (int*)  (ws + 2 * NODE_I);
    int*   cursor   = (int*)  (ws + 3 * NODE_I);
    int*   bsums    = (int*)  (ws + 4 * NODE_I);
    int*   gstart   = (int*)  (ws + 4 * NODE_I + 8192);
    int*   esrc     = (int*)  (ws + 5 * NODE_I);                       // 3.2 MB (4 MB slot)
    unsigned short* xb  = (unsigned short*)(ws + 5 * NODE_I + 4 * MB); // N_PAD*96*2 = 9.6 MB (10 MB slot)
    unsigned short* W1f = (unsigned short*)(ws + 5 * NODE_I + 14 * MB);      // 24 KB
    unsigned short* W2f = (unsigned short*)(ws + 5 * NODE_I + 14 * MB + 65536); // 32 KB
    unsigned short* hp  = (unsigned short*)(ws + 5 * NODE_I + 15 * MB);      // N_PAD*128*2 = 12.8 MB (13 MB)
    unsigned short* h   = (unsigned short*)(ws + 5 * NODE_I + 28 * MB);      // 12.8 MB

    const int NB_N  = (N_NODES + 255) / 256;              // 196
    const int NB_E  = (N_EDGES + 255) / 256;              // 3125
    const int NB_CV = (N_NODES * F_IN / 8 + 255) / 256;   // 2344
    const int NB_G  = N_PAD / 64;                         // 782
    const int NB_AG = (N_NODES + 3) / 4;                  // 12500

    // ---- counting sort of edges by dst (once, reused by both layers) ----
    fill_i32<<<NB_N, 256, 0, stream>>>(cnt, 0, N_NODES);
    hist_dst<<<NB_E, 256, 0, stream>>>(dst, cnt);
    scan_blocks<<<NB_SCAN, 256, 0, stream>>>(cnt, rowstart, bsums);
    scan_bsums<<<1, 256, 0, stream>>>(bsums);
    finish_scan<<<NB_SCAN, 256, 0, stream>>>(rowstart, bsums, cursor, cnt, dinv);
    scatter_ids<<<NB_E, 256, 0, stream>>>(src, dst, cursor, esrc);

    // ---- dtype prep ----
    convert_x<<<NB_CV, 256, 0, stream>>>(x, xb);
    prep_W<F_IN><<<6, 256, 0, stream>>>(W1, W1f);   // 8*3*64 = 1536 frags
    prep_W<HID><<<8, 256, 0, stream>>>(W2, W2f);    // 8*4*64 = 2048 frags

    // ---- layer 1 ----
    gemm_mfma<F_IN><<<NB_G, 256, 0, stream>>>(xb, W1f, dinv, hp);
    aggregate_bf16<<<NB_AG, 256, 0, stream>>>((const unsigned*)hp, esrc, rowstart, cnt, dinv, b1, (unsigned*)h);

    // ---- layer 2 ----
    gemm_mfma<HID><<<NB_G, 256, 0, stream>>>(h, W2f, dinv, hp);
    aggregate_bf16<<<NB_AG, 256, 0, stream>>>((const unsigned*)hp, esrc, rowstart, cnt, dinv, b2, (unsigned*)h);

    // ---- pooling + head ----
    graph_bounds<<<3, 256, 0, stream>>>(batch, gstart);
    pool_head<<<N_GRAPHS, 128, 0, stream>>>(h, gstart, Wlin, blin, out);
}

// Round 6
// 305.465 us; speedup vs baseline: 9.9447x; 1.0699x over previous
//
#include <hip/hip_runtime.h>

#define N_NODES 50000
#define N_PAD   50048   // 782 * 64, padded row count for MFMA tiles
#define N_EDGES 800000
#define N_GRAPHS 512
#define F_IN 96
#define HID 128
#define NB_SCAN 196     // ceil(50000/256)
#define NBUCK 196       // buckets of 256 nodes (dst >> 8)
#define CHUNK 4096      // edges per phase-A block

typedef __bf16 bf16x8 __attribute__((ext_vector_type(8)));
typedef float  f32x4  __attribute__((ext_vector_type(4)));

__device__ __forceinline__ unsigned short f2bf(float f) {
    union { float f; unsigned u; } v; v.f = f;
    unsigned r = v.u + 0x7FFFu + ((v.u >> 16) & 1u);  // RNE
    return (unsigned short)(r >> 16);
}
__device__ __forceinline__ float bflo(unsigned u) {
    union { unsigned u; float f; } v; v.u = u << 16; return v.f;
}
__device__ __forceinline__ float bfhi(unsigned u) {
    union { unsigned u; float f; } v; v.u = u & 0xFFFF0000u; return v.f;
}

// ---------------- histogram + scan (rowstart) ----------------

__global__ __launch_bounds__(256) void hist_dst(const int* __restrict__ dst,
                                                int* __restrict__ cnt) {
    int e = blockIdx.x * 256 + threadIdx.x;
    if (e < N_EDGES) atomicAdd(&cnt[dst[e]], 1);
}

__global__ __launch_bounds__(256) void scan_blocks(const int* __restrict__ cnt,
                                                   int* __restrict__ rowstart,
                                                   int* __restrict__ bsums) {
    __shared__ int s[256];
    int i = blockIdx.x * 256 + threadIdx.x;
    int v = (i < N_NODES) ? cnt[i] : 0;
    s[threadIdx.x] = v;
    __syncthreads();
#pragma unroll
    for (int off = 1; off < 256; off <<= 1) {
        int t = 0;
        if (threadIdx.x >= off) t = s[threadIdx.x - off];
        __syncthreads();
        if (threadIdx.x >= off) s[threadIdx.x] += t;
        __syncthreads();
    }
    if (i < N_NODES) rowstart[i] = s[threadIdx.x] - v;
    if (threadIdx.x == 255) bsums[blockIdx.x] = s[255];
}

__global__ __launch_bounds__(256) void scan_bsums(int* __restrict__ bsums) {
    __shared__ int s[256];
    int v = (threadIdx.x < NB_SCAN) ? bsums[threadIdx.x] : 0;
    s[threadIdx.x] = v;
    __syncthreads();
#pragma unroll
    for (int off = 1; off < 256; off <<= 1) {
        int t = 0;
        if (threadIdx.x >= off) t = s[threadIdx.x - off];
        __syncthreads();
        if (threadIdx.x >= off) s[threadIdx.x] += t;
        __syncthreads();
    }
    if (threadIdx.x < NB_SCAN) bsums[threadIdx.x] = s[threadIdx.x] - v;
}

__global__ __launch_bounds__(256) void finish_scan(int* __restrict__ rowstart,
                                                   const int* __restrict__ bsums,
                                                   const int* __restrict__ cnt,
                                                   float* __restrict__ dinv) {
    int i = blockIdx.x * 256 + threadIdx.x;
    if (i < N_NODES) {
        rowstart[i] += bsums[blockIdx.x];
        dinv[i] = rsqrtf((float)cnt[i] + 1.0f);
    }
}

__global__ __launch_bounds__(256) void init_bcur(const int* __restrict__ rowstart,
                                                 int* __restrict__ bcur) {
    int b = threadIdx.x;
    if (b < NBUCK) bcur[b] = rowstart[b * 256];
}

// ---------------- two-phase edge sort (kills write amplification) ----------------

// Phase A: block-local histogram over 196 buckets, reserve contiguous runs,
// scatter (src,dst) pairs bucket-grouped into ebuf.
__global__ __launch_bounds__(256) void scatter_pairs(const int* __restrict__ src,
                                                     const int* __restrict__ dst,
                                                     int* __restrict__ bcur,
                                                     uint2* __restrict__ ebuf) {
    __shared__ int bhist[NBUCK];
    __shared__ int goff[NBUCK];
    __shared__ int lcur[NBUCK];
    int tid = threadIdx.x;
    int e0 = blockIdx.x * CHUNK;
    int e1 = min(e0 + CHUNK, N_EDGES);
    if (tid < NBUCK) bhist[tid] = 0;
    __syncthreads();
    for (int e = e0 + tid; e < e1; e += 256)
        atomicAdd(&bhist[dst[e] >> 8], 1);
    __syncthreads();
    if (tid < NBUCK) {
        int c = bhist[tid];
        goff[tid] = (c > 0) ? atomicAdd(&bcur[tid], c) : 0;
        lcur[tid] = 0;
    }
    __syncthreads();
    for (int e = e0 + tid; e < e1; e += 256) {
        int d = dst[e];
        int b = d >> 8;
        int slot = atomicAdd(&lcur[b], 1);
        ebuf[goff[b] + slot] = make_uint2((unsigned)src[e], (unsigned)d);
    }
}

// Phase B: one block per bucket; LDS per-node cursors; final esrc writes land
// in this block's private contiguous region -> full-line writebacks.
__global__ __launch_bounds__(256) void bucket_sort(const uint2* __restrict__ ebuf,
                                                   const int* __restrict__ rowstart,
                                                   int* __restrict__ esrc) {
    __shared__ int ncur[256];
    int b = blockIdx.x;
    int tid = threadIdx.x;
    int nbase = b * 256;
    int node = nbase + tid;
    ncur[tid] = (node < N_NODES) ? rowstart[node] : 0;
    int r0 = rowstart[nbase];
    int r1 = (b == NBUCK - 1) ? N_EDGES : rowstart[nbase + 256];
    __syncthreads();
    for (int i = r0 + tid; i < r1; i += 256) {
        uint2 p = ebuf[i];
        int ln = (int)p.y - nbase;
        int pos = atomicAdd(&ncur[ln], 1);
        esrc[pos] = (int)p.x;
    }
}

// ---------------- bf16 conversion / W pre-swizzle ----------------

__global__ __launch_bounds__(256) void convert_x(const float* __restrict__ x,
                                                 unsigned short* __restrict__ xb) {
    int i = blockIdx.x * 256 + threadIdx.x;
    if (i >= N_NODES * F_IN / 8) return;
    const float4* p = (const float4*)(x + (long)i * 8);
    float4 a = p[0], b = p[1];
    uint4 o;
    o.x = (unsigned)f2bf(a.x) | ((unsigned)f2bf(a.y) << 16);
    o.y = (unsigned)f2bf(a.z) | ((unsigned)f2bf(a.w) << 16);
    o.z = (unsigned)f2bf(b.x) | ((unsigned)f2bf(b.y) << 16);
    o.w = (unsigned)f2bf(b.z) | ((unsigned)f2bf(b.w) << 16);
    *(uint4*)(xb + (long)i * 8) = o;
}

template <int K>
__global__ __launch_bounds__(256) void prep_W(const float* __restrict__ W,
                                              unsigned short* __restrict__ Wf) {
    const int KS = K / 32;
    int idx = blockIdx.x * 256 + threadIdx.x;
    if (idx >= 8 * KS * 64) return;
    int t = idx / (KS * 64);
    int rem = idx % (KS * 64);
    int s = rem / 64;
    int l = rem & 63;
    int n = t * 16 + (l & 15);
    int k0 = s * 32 + (l >> 4) * 8;
    unsigned short v[8];
#pragma unroll
    for (int j = 0; j < 8; ++j) v[j] = f2bf(W[(long)(k0 + j) * 128 + n]);
    uint4 o;
    o.x = (unsigned)v[0] | ((unsigned)v[1] << 16);
    o.y = (unsigned)v[2] | ((unsigned)v[3] << 16);
    o.z = (unsigned)v[4] | ((unsigned)v[5] << 16);
    o.w = (unsigned)v[6] | ((unsigned)v[7] << 16);
    *(uint4*)(Wf + (long)idx * 8) = o;
}

// ---------------- MFMA GEMM (unchanged from R5) ----------------

template <int K>
__global__ __launch_bounds__(256) void gemm_mfma(const unsigned short* __restrict__ A,
                                                 const unsigned short* __restrict__ Wf,
                                                 const float* __restrict__ dinv,
                                                 unsigned short* __restrict__ hp) {
    const int KS = K / 32;
    const int wave = threadIdx.x >> 6;
    const int lane = threadIdx.x & 63;
    const int r0 = blockIdx.x * 64 + wave * 16;

    f32x4 acc[8];
#pragma unroll
    for (int t = 0; t < 8; ++t) acc[t] = (f32x4){0.f, 0.f, 0.f, 0.f};

    const int arow = r0 + (lane & 15);
    const int kq = (lane >> 4) * 8;

    for (int s = 0; s < KS; ++s) {
        union { uint4 u; bf16x8 b; } af;
        af.u = *(const uint4*)(A + (long)arow * K + s * 32 + kq);
#pragma unroll
        for (int t = 0; t < 8; ++t) {
            union { uint4 u; bf16x8 b; } bfr;
            bfr.u = *(const uint4*)(Wf + ((long)(t * KS + s) * 64 + lane) * 8);
            acc[t] = __builtin_amdgcn_mfma_f32_16x16x32_bf16(af.b, bfr.b, acc[t], 0, 0, 0);
        }
    }

    const int q = lane >> 4;
    float dv[4];
#pragma unroll
    for (int r = 0; r < 4; ++r) {
        int row = r0 + q * 4 + r;
        dv[r] = dinv[row < N_NODES ? row : 0];
    }
#pragma unroll
    for (int t = 0; t < 8; ++t) {
        int col = t * 16 + (lane & 15);
#pragma unroll
        for (int r = 0; r < 4; ++r) {
            int row = r0 + q * 4 + r;
            if (row < N_NODES)
                hp[(long)row * 128 + col] = f2bf(acc[t][r] * dv[r]);
        }
    }
}

// ---------------- aggregate: 16 lanes x dwordx4, 4 edges per load instr ----------------
// wave per node; lane = (eslot = lane>>4, ugrp = lane&15); row = 16 uint4 = 128 bf16.
__global__ __launch_bounds__(256) void aggregate4(const uint4* __restrict__ hp4,
                                                  const int* __restrict__ esrc,
                                                  const int* __restrict__ rowstart,
                                                  const int* __restrict__ cnt,
                                                  const float* __restrict__ dinv,
                                                  const float* __restrict__ bias,
                                                  uint4* __restrict__ hout4) {
    int node = blockIdx.x * 4 + (threadIdx.x >> 6);
    if (node >= N_NODES) return;
    int lane = threadIdx.x & 63;
    int eslot = lane >> 4;
    int ug = lane & 15;
    int start = rowstart[node];
    int end = start + cnt[node];

    float a[8];
#pragma unroll
    for (int k = 0; k < 8; ++k) a[k] = 0.f;

    for (int j = start; j < end; j += 8) {
        int e0 = j + eslot;
        int e1 = j + 4 + eslot;
        if (e0 < end) {
            int s = esrc[e0];
            uint4 v = hp4[(long)s * 16 + ug];
            a[0] += bflo(v.x); a[1] += bfhi(v.x);
            a[2] += bflo(v.y); a[3] += bfhi(v.y);
            a[4] += bflo(v.z); a[5] += bfhi(v.z);
            a[6] += bflo(v.w); a[7] += bfhi(v.w);
        }
        if (e1 < end) {
            int s = esrc[e1];
            uint4 v = hp4[(long)s * 16 + ug];
            a[0] += bflo(v.x); a[1] += bfhi(v.x);
            a[2] += bflo(v.y); a[3] += bfhi(v.y);
            a[4] += bflo(v.z); a[5] += bfhi(v.z);
            a[6] += bflo(v.w); a[7] += bfhi(v.w);
        }
    }

    // reduce across the 4 eslots (same ugrp lives in lanes l, l^16, l^32, l^48)
#pragma unroll
    for (int k = 0; k < 8; ++k) {
        a[k] += __shfl_xor(a[k], 16);
        a[k] += __shfl_xor(a[k], 32);
    }

    if (eslot == 0) {
        uint4 vs = hp4[(long)node * 16 + ug];
        a[0] += bflo(vs.x); a[1] += bfhi(vs.x);
        a[2] += bflo(vs.y); a[3] += bfhi(vs.y);
        a[4] += bflo(vs.z); a[5] += bfhi(vs.z);
        a[6] += bflo(vs.w); a[7] += bfhi(vs.w);
        float d = dinv[node];
        float4 b0 = *(const float4*)(bias + ug * 8);
        float4 b1 = *(const float4*)(bias + ug * 8 + 4);
        float o0 = fmaxf(d * a[0] + b0.x, 0.f), o1 = fmaxf(d * a[1] + b0.y, 0.f);
        float o2 = fmaxf(d * a[2] + b0.z, 0.f), o3 = fmaxf(d * a[3] + b0.w, 0.f);
        float o4 = fmaxf(d * a[4] + b1.x, 0.f), o5 = fmaxf(d * a[5] + b1.y, 0.f);
        float o6 = fmaxf(d * a[6] + b1.z, 0.f), o7 = fmaxf(d * a[7] + b1.w, 0.f);
        uint4 o;
        o.x = (unsigned)f2bf(o0) | ((unsigned)f2bf(o1) << 16);
        o.y = (unsigned)f2bf(o2) | ((unsigned)f2bf(o3) << 16);
        o.z = (unsigned)f2bf(o4) | ((unsigned)f2bf(o5) << 16);
        o.w = (unsigned)f2bf(o6) | ((unsigned)f2bf(o7) << 16);
        hout4[(long)node * 16 + ug] = o;
    }
}

// ---------------- pooling + head (bounds fused) ----------------

__global__ __launch_bounds__(128) void pool_head(const unsigned short* __restrict__ h,
                                                 const int* __restrict__ batch,
                                                 const float* __restrict__ Wlin,
                                                 const float* __restrict__ blin,
                                                 float* __restrict__ out) {
    __shared__ int bnd[2];
    int g = blockIdx.x;
    int c = threadIdx.x;
    if (c < 2) {
        int target = g + c;
        int lo = 0, hi = N_NODES;
        while (lo < hi) {
            int mid = (lo + hi) >> 1;
            if (batch[mid] < target) lo = mid + 1;
            else hi = mid;
        }
        bnd[c] = lo;
    }
    __syncthreads();
    int s = bnd[0], e = bnd[1];

    float sum = 0.f;
    for (int i = s; i < e; ++i) {
        union { unsigned u; float f; } v;
        v.u = (unsigned)h[(long)i * 128 + c] << 16;
        sum += v.f;
    }
    float inv = (e > s) ? 1.0f / (float)(e - s) : 1.0f;
    float m = sum * inv;

    __shared__ float red[128][2];
    red[c][0] = m * Wlin[c * 2 + 0];
    red[c][1] = m * Wlin[c * 2 + 1];
    __syncthreads();
#pragma unroll
    for (int off = 64; off > 0; off >>= 1) {
        if (c < off) {
            red[c][0] += red[c + off][0];
            red[c][1] += red[c + off][1];
        }
        __syncthreads();
    }
    if (c < 2) out[g * 2 + c] = red[0][c] + blin[c];
}

extern "C" void kernel_launch(void* const* d_in, const int* in_sizes, int n_in,
                              void* d_out, int out_size, void* d_ws, size_t ws_size,
                              hipStream_t stream) {
    const float* x    = (const float*)d_in[0];
    const int*   ei   = (const int*)d_in[1];
    const int*   batch= (const int*)d_in[2];
    const float* W1   = (const float*)d_in[4];
    const float* b1   = (const float*)d_in[5];
    const float* W2   = (const float*)d_in[6];
    const float* b2   = (const float*)d_in[7];
    const float* Wlin = (const float*)d_in[8];
    const float* blin = (const float*)d_in[9];
    float* out = (float*)d_out;

    const int* src = ei;
    const int* dst = ei + N_EDGES;

    char* ws = (char*)d_ws;
    const size_t SLOT = 256 * 1024;
    const size_t MB = 1024 * 1024;

    float* dinv     = (float*)(ws);
    int*   cnt      = (int*)  (ws + 1 * SLOT);
    int*   rowstart = (int*)  (ws + 2 * SLOT);
    int*   bsums    = (int*)  (ws + 3 * SLOT);
    int*   bcur     = (int*)  (ws + 4 * SLOT);
    uint2* ebuf     = (uint2*)(ws + 5 * SLOT);          // 6.4 MB (to 8 MB mark)
    int*   esrc     = (int*)  (ws + 8 * MB);            // 3.2 MB
    unsigned short* xb  = (unsigned short*)(ws + 12 * MB);   // 9.61 MB (N_PAD rows)
    unsigned short* W1f = (unsigned short*)(ws + 22 * MB);   // 24 KB
    unsigned short* W2f = (unsigned short*)(ws + 22 * MB + 65536);  // 32 KB
    unsigned short* hp  = (unsigned short*)(ws + 23 * MB);   // 12.85 MB
    unsigned short* h   = (unsigned short*)(ws + 36 * MB);   // 12.85 MB

    const int NB_E  = (N_EDGES + 255) / 256;              // 3125
    const int NB_CV = (N_NODES * F_IN / 8 + 255) / 256;   // 2344
    const int NB_G  = N_PAD / 64;                         // 782
    const int NB_AG = (N_NODES + 3) / 4;                  // 12500
    const int NB_A  = (N_EDGES + CHUNK - 1) / CHUNK;      // 196

    // ---- edge CSR build (once, reused by both layers) ----
    hipMemsetAsync(cnt, 0, (size_t)N_NODES * 4, stream);
    hist_dst<<<NB_E, 256, 0, stream>>>(dst, cnt);
    scan_blocks<<<NB_SCAN, 256, 0, stream>>>(cnt, rowstart, bsums);
    scan_bsums<<<1, 256, 0, stream>>>(bsums);
    finish_scan<<<NB_SCAN, 256, 0, stream>>>(rowstart, bsums, cnt, dinv);
    init_bcur<<<1, 256, 0, stream>>>(rowstart, bcur);
    scatter_pairs<<<NB_A, 256, 0, stream>>>(src, dst, bcur, ebuf);
    bucket_sort<<<NBUCK, 256, 0, stream>>>(ebuf, rowstart, esrc);

    // ---- dtype prep ----
    convert_x<<<NB_CV, 256, 0, stream>>>(x, xb);
    prep_W<F_IN><<<6, 256, 0, stream>>>(W1, W1f);
    prep_W<HID><<<8, 256, 0, stream>>>(W2, W2f);

    // ---- layer 1 ----
    gemm_mfma<F_IN><<<NB_G, 256, 0, stream>>>(xb, W1f, dinv, hp);
    aggregate4<<<NB_AG, 256, 0, stream>>>((const uint4*)hp, esrc, rowstart, cnt, dinv, b1, (uint4*)h);

    // ---- layer 2 ----
    gemm_mfma<HID><<<NB_G, 256, 0, stream>>>(h, W2f, dinv, hp);
    aggregate4<<<NB_AG, 256, 0, stream>>>((const uint4*)hp, esrc, rowstart, cnt, dinv, b2, (uint4*)h);

    // ---- pooling + head ----
    pool_head<<<N_GRAPHS, 128, 0, stream>>>(h, batch, Wlin, blin, out);
}

// Round 7
// 283.375 us; speedup vs baseline: 10.7199x; 1.0780x over previous
//
#include <hip/hip_runtime.h>

#define N_NODES 50000
#define N_PAD   50048   // 782 * 64, padded row count for MFMA tiles
#define N_EDGES 800000
#define N_GRAPHS 512
#define F_IN 96
#define HID 128
#define NBUCK 196       // buckets of 256 nodes (dst >> 8)
#define CHUNK 4096      // edges per scatter_pairs block

typedef __bf16 bf16x8 __attribute__((ext_vector_type(8)));
typedef float  f32x4  __attribute__((ext_vector_type(4)));

__device__ __forceinline__ unsigned short f2bf(float f) {
    union { float f; unsigned u; } v; v.f = f;
    unsigned r = v.u + 0x7FFFu + ((v.u >> 16) & 1u);  // RNE
    return (unsigned short)(r >> 16);
}
__device__ __forceinline__ float bflo(unsigned u) {
    union { unsigned u; float f; } v; v.u = u << 16; return v.f;
}
__device__ __forceinline__ float bfhi(unsigned u) {
    union { unsigned u; float f; } v; v.u = u & 0xFFFF0000u; return v.f;
}

// ---------------- degree histogram (4 edges/thread) ----------------

__global__ __launch_bounds__(256) void hist_dst(const uint4* __restrict__ dst4,
                                                int* __restrict__ cnt) {
    int i = blockIdx.x * 256 + threadIdx.x;
    if (i >= N_EDGES / 4) return;
    uint4 d = dst4[i];
    atomicAdd(&cnt[d.x], 1);
    atomicAdd(&cnt[d.y], 1);
    atomicAdd(&cnt[d.z], 1);
    atomicAdd(&cnt[d.w], 1);
}

// dinv[i] = rsqrt(cnt[i]+1); bsum[b] = sum of cnt over bucket b (256 nodes)
__global__ __launch_bounds__(256) void node_pre(const int* __restrict__ cnt,
                                                float* __restrict__ dinv,
                                                int* __restrict__ bsum) {
    __shared__ int s[256];
    int i = blockIdx.x * 256 + threadIdx.x;
    int c = (i < N_NODES) ? cnt[i] : 0;
    if (i < N_NODES) dinv[i] = rsqrtf((float)c + 1.0f);
    s[threadIdx.x] = c;
    __syncthreads();
#pragma unroll
    for (int off = 128; off > 0; off >>= 1) {
        if (threadIdx.x < off) s[threadIdx.x] += s[threadIdx.x + off];
        __syncthreads();
    }
    if (threadIdx.x == 0) bsum[blockIdx.x] = s[0];
}

// exclusive scan of bsum -> bstart[0..NBUCK]; bcur = bstart
__global__ __launch_bounds__(256) void scan196(const int* __restrict__ bsum,
                                               int* __restrict__ bstart,
                                               int* __restrict__ bcur) {
    __shared__ int s[256];
    int v = (threadIdx.x < NBUCK) ? bsum[threadIdx.x] : 0;
    s[threadIdx.x] = v;
    __syncthreads();
#pragma unroll
    for (int off = 1; off < 256; off <<= 1) {
        int t = 0;
        if (threadIdx.x >= off) t = s[threadIdx.x - off];
        __syncthreads();
        if (threadIdx.x >= off) s[threadIdx.x] += t;
        __syncthreads();
    }
    if (threadIdx.x < NBUCK) {
        int ex = s[threadIdx.x] - v;
        bstart[threadIdx.x] = ex;
        bcur[threadIdx.x] = ex;
    }
    if (threadIdx.x == 0) bstart[NBUCK] = N_EDGES;
}

// ---------------- two-phase edge sort ----------------

__global__ __launch_bounds__(256) void scatter_pairs(const int* __restrict__ src,
                                                     const int* __restrict__ dst,
                                                     int* __restrict__ bcur,
                                                     uint2* __restrict__ ebuf) {
    __shared__ int bhist[NBUCK];
    __shared__ int goff[NBUCK];
    __shared__ int lcur[NBUCK];
    int tid = threadIdx.x;
    int e0 = blockIdx.x * CHUNK;
    int e1 = min(e0 + CHUNK, N_EDGES);
    if (tid < NBUCK) bhist[tid] = 0;
    __syncthreads();
    for (int e = e0 + tid; e < e1; e += 256)
        atomicAdd(&bhist[dst[e] >> 8], 1);
    __syncthreads();
    if (tid < NBUCK) {
        int c = bhist[tid];
        goff[tid] = (c > 0) ? atomicAdd(&bcur[tid], c) : 0;
        lcur[tid] = 0;
    }
    __syncthreads();
    for (int e = e0 + tid; e < e1; e += 256) {
        int d = dst[e];
        int b = d >> 8;
        int slot = atomicAdd(&lcur[b], 1);
        ebuf[goff[b] + slot] = make_uint2((unsigned)src[e], (unsigned)d);
    }
}

// per-bucket: scan cnt -> rowstart (global write), place esrc in private region
__global__ __launch_bounds__(256) void bucket_sort(const uint2* __restrict__ ebuf,
                                                   const int* __restrict__ cnt,
                                                   const int* __restrict__ bstart,
                                                   int* __restrict__ rowstart,
                                                   int* __restrict__ esrc) {
    __shared__ int ssc[256];
    __shared__ int ncur[256];
    int b = blockIdx.x;
    int tid = threadIdx.x;
    int nbase = b * 256;
    int node = nbase + tid;
    int c = (node < N_NODES) ? cnt[node] : 0;
    ssc[tid] = c;
    __syncthreads();
#pragma unroll
    for (int off = 1; off < 256; off <<= 1) {
        int t = 0;
        if (tid >= off) t = ssc[tid - off];
        __syncthreads();
        if (tid >= off) ssc[tid] += t;
        __syncthreads();
    }
    int rs = bstart[b] + ssc[tid] - c;  // exclusive within bucket + bucket base
    ncur[tid] = rs;
    if (node < N_NODES) rowstart[node] = rs;
    int r0 = bstart[b], r1 = bstart[b + 1];
    __syncthreads();
    for (int i = r0 + tid; i < r1; i += 256) {
        uint2 p = ebuf[i];
        int pos = atomicAdd(&ncur[(int)p.y - nbase], 1);
        esrc[pos] = (int)p.x;
    }
}

// ---------------- W pre-swizzle (both layers, one dispatch) ----------------
// frag idx = (t*KS + s)*64 + lane; element j: B[k = s*32 + (lane>>4)*8 + j][n = t*16 + (lane&15)]
__device__ __forceinline__ void prep_one(const float* __restrict__ W, int KS, int idx,
                                         unsigned short* __restrict__ Wf) {
    int t = idx / (KS * 64);
    int rem = idx % (KS * 64);
    int s = rem / 64;
    int l = rem & 63;
    int n = t * 16 + (l & 15);
    int k0 = s * 32 + (l >> 4) * 8;
    unsigned short v[8];
#pragma unroll
    for (int j = 0; j < 8; ++j) v[j] = f2bf(W[(long)(k0 + j) * 128 + n]);
    uint4 o;
    o.x = (unsigned)v[0] | ((unsigned)v[1] << 16);
    o.y = (unsigned)v[2] | ((unsigned)v[3] << 16);
    o.z = (unsigned)v[4] | ((unsigned)v[5] << 16);
    o.w = (unsigned)v[6] | ((unsigned)v[7] << 16);
    *(uint4*)(Wf + (long)idx * 8) = o;
}

__global__ __launch_bounds__(256) void prep_Wboth(const float* __restrict__ W1,
                                                  const float* __restrict__ W2,
                                                  unsigned short* __restrict__ W1f,
                                                  unsigned short* __restrict__ W2f) {
    int b = blockIdx.x;
    if (b < 6) {
        int idx = b * 256 + threadIdx.x;
        if (idx < 8 * 3 * 64) prep_one(W1, 3, idx, W1f);
    } else {
        int idx = (b - 6) * 256 + threadIdx.x;
        if (idx < 8 * 4 * 64) prep_one(W2, 4, idx, W2f);
    }
}

// ---------------- MFMA GEMM, layer 1: A is f32, converted in-register ----------------
__global__ __launch_bounds__(256) void gemm_mfma_f32A(const float* __restrict__ A,
                                                      const unsigned short* __restrict__ Wf,
                                                      const float* __restrict__ dinv,
                                                      unsigned short* __restrict__ hp) {
    const int KS = 3;  // K = 96
    const int wave = threadIdx.x >> 6;
    const int lane = threadIdx.x & 63;
    const int r0 = blockIdx.x * 64 + wave * 16;

    f32x4 acc[8];
#pragma unroll
    for (int t = 0; t < 8; ++t) acc[t] = (f32x4){0.f, 0.f, 0.f, 0.f};

    int arow = r0 + (lane & 15);
    if (arow >= N_NODES) arow = N_NODES - 1;  // clamp: padding rows discarded on store
    const int kq = (lane >> 4) * 8;

    for (int s = 0; s < KS; ++s) {
        const float* ap = A + (long)arow * F_IN + s * 32 + kq;
        float4 a0 = *(const float4*)(ap);
        float4 a1 = *(const float4*)(ap + 4);
        union { uint4 u; bf16x8 b; } af;
        af.u.x = (unsigned)f2bf(a0.x) | ((unsigned)f2bf(a0.y) << 16);
        af.u.y = (unsigned)f2bf(a0.z) | ((unsigned)f2bf(a0.w) << 16);
        af.u.z = (unsigned)f2bf(a1.x) | ((unsigned)f2bf(a1.y) << 16);
        af.u.w = (unsigned)f2bf(a1.z) | ((unsigned)f2bf(a1.w) << 16);
#pragma unroll
        for (int t = 0; t < 8; ++t) {
            union { uint4 u; bf16x8 b; } bfr;
            bfr.u = *(const uint4*)(Wf + ((long)(t * KS + s) * 64 + lane) * 8);
            acc[t] = __builtin_amdgcn_mfma_f32_16x16x32_bf16(af.b, bfr.b, acc[t], 0, 0, 0);
        }
    }

    const int q = lane >> 4;
    float dv[4];
#pragma unroll
    for (int r = 0; r < 4; ++r) {
        int row = r0 + q * 4 + r;
        dv[r] = dinv[row < N_NODES ? row : 0];
    }
#pragma unroll
    for (int t = 0; t < 8; ++t) {
        int col = t * 16 + (lane & 15);
#pragma unroll
        for (int r = 0; r < 4; ++r) {
            int row = r0 + q * 4 + r;
            if (row < N_NODES)
                hp[(long)row * 128 + col] = f2bf(acc[t][r] * dv[r]);
        }
    }
}

// ---------------- MFMA GEMM, layer 2: A is bf16 (h) ----------------
__global__ __launch_bounds__(256) void gemm_mfma_bf16A(const unsigned short* __restrict__ A,
                                                       const unsigned short* __restrict__ Wf,
                                                       const float* __restrict__ dinv,
                                                       unsigned short* __restrict__ hp) {
    const int KS = 4;  // K = 128
    const int wave = threadIdx.x >> 6;
    const int lane = threadIdx.x & 63;
    const int r0 = blockIdx.x * 64 + wave * 16;

    f32x4 acc[8];
#pragma unroll
    for (int t = 0; t < 8; ++t) acc[t] = (f32x4){0.f, 0.f, 0.f, 0.f};

    const int arow = r0 + (lane & 15);   // reads into ws padding are safe
    const int kq = (lane >> 4) * 8;

    for (int s = 0; s < KS; ++s) {
        union { uint4 u; bf16x8 b; } af;
        af.u = *(const uint4*)(A + (long)arow * HID + s * 32 + kq);
#pragma unroll
        for (int t = 0; t < 8; ++t) {
            union { uint4 u; bf16x8 b; } bfr;
            bfr.u = *(const uint4*)(Wf + ((long)(t * KS + s) * 64 + lane) * 8);
            acc[t] = __builtin_amdgcn_mfma_f32_16x16x32_bf16(af.b, bfr.b, acc[t], 0, 0, 0);
        }
    }

    const int q = lane >> 4;
    float dv[4];
#pragma unroll
    for (int r = 0; r < 4; ++r) {
        int row = r0 + q * 4 + r;
        dv[r] = dinv[row < N_NODES ? row : 0];
    }
#pragma unroll
    for (int t = 0; t < 8; ++t) {
        int col = t * 16 + (lane & 15);
#pragma unroll
        for (int r = 0; r < 4; ++r) {
            int row = r0 + q * 4 + r;
            if (row < N_NODES)
                hp[(long)row * 128 + col] = f2bf(acc[t][r] * dv[r]);
        }
    }
}

// ---------------- aggregate: 16 lanes x dwordx4, 4 loads in flight ----------------
__global__ __launch_bounds__(256) void aggregate4(const uint4* __restrict__ hp4,
                                                  const int* __restrict__ esrc,
                                                  const int* __restrict__ rowstart,
                                                  const int* __restrict__ cnt,
                                                  const float* __restrict__ dinv,
                                                  const float* __restrict__ bias,
                                                  uint4* __restrict__ hout4) {
    int node = blockIdx.x * 4 + (threadIdx.x >> 6);
    if (node >= N_NODES) return;
    int lane = threadIdx.x & 63;
    int eslot = lane >> 4;
    int ug = lane & 15;
    int start = rowstart[node];
    int end = start + cnt[node];

    float a[8];
#pragma unroll
    for (int k = 0; k < 8; ++k) a[k] = 0.f;

    for (int j = start; j < end; j += 16) {
        int e[4];
        uint4 v[4];
#pragma unroll
        for (int q = 0; q < 4; ++q) {
            e[q] = j + q * 4 + eslot;
            int s = esrc[min(e[q], end - 1)];
            v[q] = hp4[(long)s * 16 + ug];
        }
#pragma unroll
        for (int q = 0; q < 4; ++q) {
            if (e[q] < end) {
                a[0] += bflo(v[q].x); a[1] += bfhi(v[q].x);
                a[2] += bflo(v[q].y); a[3] += bfhi(v[q].y);
                a[4] += bflo(v[q].z); a[5] += bfhi(v[q].z);
                a[6] += bflo(v[q].w); a[7] += bfhi(v[q].w);
            }
        }
    }

    // reduce across the 4 eslots
#pragma unroll
    for (int k = 0; k < 8; ++k) {
        a[k] += __shfl_xor(a[k], 16);
        a[k] += __shfl_xor(a[k], 32);
    }

    if (eslot == 0) {
        uint4 vs = hp4[(long)node * 16 + ug];
        a[0] += bflo(vs.x); a[1] += bfhi(vs.x);
        a[2] += bflo(vs.y); a[3] += bfhi(vs.y);
        a[4] += bflo(vs.z); a[5] += bfhi(vs.z);
        a[6] += bflo(vs.w); a[7] += bfhi(vs.w);
        float d = dinv[node];
        float4 b0 = *(const float4*)(bias + ug * 8);
        float4 b1 = *(const float4*)(bias + ug * 8 + 4);
        float o0 = fmaxf(d * a[0] + b0.x, 0.f), o1 = fmaxf(d * a[1] + b0.y, 0.f);
        float o2 = fmaxf(d * a[2] + b0.z, 0.f), o3 = fmaxf(d * a[3] + b0.w, 0.f);
        float o4 = fmaxf(d * a[4] + b1.x, 0.f), o5 = fmaxf(d * a[5] + b1.y, 0.f);
        float o6 = fmaxf(d * a[6] + b1.z, 0.f), o7 = fmaxf(d * a[7] + b1.w, 0.f);
        uint4 o;
        o.x = (unsigned)f2bf(o0) | ((unsigned)f2bf(o1) << 16);
        o.y = (unsigned)f2bf(o2) | ((unsigned)f2bf(o3) << 16);
        o.z = (unsigned)f2bf(o4) | ((unsigned)f2bf(o5) << 16);
        o.w = (unsigned)f2bf(o6) | ((unsigned)f2bf(o7) << 16);
        hout4[(long)node * 16 + ug] = o;
    }
}

// ---------------- pooling + head ----------------

__global__ __launch_bounds__(128) void pool_head(const unsigned short* __restrict__ h,
                                                 const int* __restrict__ batch,
                                                 const float* __restrict__ Wlin,
                                                 const float* __restrict__ blin,
                                                 float* __restrict__ out) {
    __shared__ int bnd[2];
    int g = blockIdx.x;
    int c = threadIdx.x;
    if (c < 2) {
        int target = g + c;
        int lo = 0, hi = N_NODES;
        while (lo < hi) {
            int mid = (lo + hi) >> 1;
            if (batch[mid] < target) lo = mid + 1;
            else hi = mid;
        }
        bnd[c] = lo;
    }
    __syncthreads();
    int s = bnd[0], e = bnd[1];

    float sum = 0.f;
    for (int i = s; i < e; ++i) {
        union { unsigned u; float f; } v;
        v.u = (unsigned)h[(long)i * 128 + c] << 16;
        sum += v.f;
    }
    float inv = (e > s) ? 1.0f / (float)(e - s) : 1.0f;
    float m = sum * inv;

    __shared__ float red[128][2];
    red[c][0] = m * Wlin[c * 2 + 0];
    red[c][1] = m * Wlin[c * 2 + 1];
    __syncthreads();
#pragma unroll
    for (int off = 64; off > 0; off >>= 1) {
        if (c < off) {
            red[c][0] += red[c + off][0];
            red[c][1] += red[c + off][1];
        }
        __syncthreads();
    }
    if (c < 2) out[g * 2 + c] = red[0][c] + blin[c];
}

extern "C" void kernel_launch(void* const* d_in, const int* in_sizes, int n_in,
                              void* d_out, int out_size, void* d_ws, size_t ws_size,
                              hipStream_t stream) {
    const float* x    = (const float*)d_in[0];
    const int*   ei   = (const int*)d_in[1];
    const int*   batch= (const int*)d_in[2];
    const float* W1   = (const float*)d_in[4];
    const float* b1   = (const float*)d_in[5];
    const float* W2   = (const float*)d_in[6];
    const float* b2   = (const float*)d_in[7];
    const float* Wlin = (const float*)d_in[8];
    const float* blin = (const float*)d_in[9];
    float* out = (float*)d_out;

    const int* src = ei;
    const int* dst = ei + N_EDGES;

    char* ws = (char*)d_ws;
    const size_t KB = 1024;
    const size_t MB = 1024 * 1024;

    float* dinv     = (float*)(ws);                      // 200 KB
    int*   cnt      = (int*)  (ws + 256 * KB);           // 200 KB
    int*   rowstart = (int*)  (ws + 512 * KB);           // 200 KB
    int*   bsum     = (int*)  (ws + 768 * KB);           // 784 B
    int*   bstart   = (int*)  (ws + 768 * KB + 4096);    // 788 B
    int*   bcur     = (int*)  (ws + 768 * KB + 8192);    // 784 B
    uint2* ebuf     = (uint2*)(ws + 1 * MB);             // 6.4 MB
    int*   esrc     = (int*)  (ws + 8 * MB);             // 3.2 MB
    unsigned short* W1f = (unsigned short*)(ws + 12 * MB);            // 24 KB
    unsigned short* W2f = (unsigned short*)(ws + 12 * MB + 64 * KB);  // 32 KB
    unsigned short* hp  = (unsigned short*)(ws + 13 * MB);            // 12.82 MB (N_PAD rows)
    unsigned short* h   = (unsigned short*)(ws + 26 * MB);            // 12.82 MB

    const int NB_H  = (N_EDGES / 4 + 255) / 256;          // 782
    const int NB_G  = N_PAD / 64;                         // 782
    const int NB_AG = (N_NODES + 3) / 4;                  // 12500
    const int NB_A  = (N_EDGES + CHUNK - 1) / CHUNK;      // 196

    // ---- CSR build (reused by both layers) ----
    hipMemsetAsync(cnt, 0, (size_t)N_NODES * 4, stream);
    hist_dst<<<NB_H, 256, 0, stream>>>((const uint4*)dst, cnt);
    node_pre<<<NBUCK, 256, 0, stream>>>(cnt, dinv, bsum);
    scan196<<<1, 256, 0, stream>>>(bsum, bstart, bcur);
    scatter_pairs<<<NB_A, 256, 0, stream>>>(src, dst, bcur, ebuf);
    bucket_sort<<<NBUCK, 256, 0, stream>>>(ebuf, cnt, bstart, rowstart, esrc);

    // ---- weight prep (single dispatch) ----
    prep_Wboth<<<14, 256, 0, stream>>>(W1, W2, W1f, W2f);

    // ---- layer 1 ----
    gemm_mfma_f32A<<<NB_G, 256, 0, stream>>>(x, W1f, dinv, hp);
    aggregate4<<<NB_AG, 256, 0, stream>>>((const uint4*)hp, esrc, rowstart, cnt, dinv, b1, (uint4*)h);

    // ---- layer 2 ----
    gemm_mfma_bf16A<<<NB_G, 256, 0, stream>>>(h, W2f, dinv, hp);
    aggregate4<<<NB_AG, 256, 0, stream>>>((const uint4*)hp, esrc, rowstart, cnt, dinv, b2, (uint4*)h);

    // ---- pooling + head ----
    pool_head<<<N_GRAPHS, 128, 0, stream>>>(h, batch, Wlin, blin, out);
}

// Round 8
// 253.146 us; speedup vs baseline: 12.0000x; 1.1194x over previous
//
#include <hip/hip_runtime.h>

#define N_NODES 50000
#define N_PAD   50048   // 782 * 64, padded row count for MFMA tiles
#define N_EDGES 800000
#define N_GRAPHS 512
#define F_IN 96
#define HID 128
#define NBUCK 196       // buckets of 256 nodes (dst >> 8)
#define CHUNK 4096      // edges per chunk block (196 * 4096 >= 800000)

typedef __bf16 bf16x8 __attribute__((ext_vector_type(8)));
typedef float  f32x4  __attribute__((ext_vector_type(4)));

__device__ __forceinline__ unsigned short f2bf(float f) {
    union { float f; unsigned u; } v; v.f = f;
    unsigned r = v.u + 0x7FFFu + ((v.u >> 16) & 1u);  // RNE
    return (unsigned short)(r >> 16);
}
__device__ __forceinline__ float bflo(unsigned u) {
    union { unsigned u; float f; } v; v.u = u << 16; return v.f;
}
__device__ __forceinline__ float bfhi(unsigned u) {
    union { unsigned u; float f; } v; v.u = u & 0xFFFF0000u; return v.f;
}

// ---------------- W pre-swizzle helper ----------------
// frag idx = (t*KS + s)*64 + lane; element j: B[k = s*32 + (lane>>4)*8 + j][n = t*16 + (lane&15)]
__device__ __forceinline__ void prep_one(const float* __restrict__ W, int KS, int idx,
                                         unsigned short* __restrict__ Wf) {
    int t = idx / (KS * 64);
    int rem = idx % (KS * 64);
    int s = rem / 64;
    int l = rem & 63;
    int n = t * 16 + (l & 15);
    int k0 = s * 32 + (l >> 4) * 8;
    unsigned short v[8];
#pragma unroll
    for (int j = 0; j < 8; ++j) v[j] = f2bf(W[(long)(k0 + j) * 128 + n]);
    uint4 o;
    o.x = (unsigned)v[0] | ((unsigned)v[1] << 16);
    o.y = (unsigned)v[2] | ((unsigned)v[3] << 16);
    o.z = (unsigned)v[4] | ((unsigned)v[5] << 16);
    o.w = (unsigned)v[6] | ((unsigned)v[7] << 16);
    *(uint4*)(Wf + (long)idx * 8) = o;
}

// ---------------- K1: per-chunk bucket histogram (+ fused weight prep) ----------------
// blocks 0..195: bh[c][b] = # edges of chunk c in bucket b.  blocks 196..209: prep W frags.
__global__ __launch_bounds__(256) void bucket_hist(const int* __restrict__ dst,
                                                   const float* __restrict__ W1,
                                                   const float* __restrict__ W2,
                                                   unsigned short* __restrict__ W1f,
                                                   unsigned short* __restrict__ W2f,
                                                   int* __restrict__ bh) {
    int blk = blockIdx.x;
    if (blk >= NBUCK) {
        int b = blk - NBUCK;
        if (b < 6) {
            int idx = b * 256 + threadIdx.x;
            if (idx < 8 * 3 * 64) prep_one(W1, 3, idx, W1f);
        } else {
            int idx = (b - 6) * 256 + threadIdx.x;
            if (idx < 8 * 4 * 64) prep_one(W2, 4, idx, W2f);
        }
        return;
    }
    __shared__ int bhist[NBUCK];
    int tid = threadIdx.x;
    if (tid < NBUCK) bhist[tid] = 0;
    __syncthreads();
    int e0 = blk * CHUNK, e1 = min(e0 + CHUNK, N_EDGES);
    for (int e = e0 + tid; e < e1; e += 256)
        atomicAdd(&bhist[dst[e] >> 8], 1);
    __syncthreads();
    if (tid < NBUCK) bh[blk * NBUCK + tid] = bhist[tid];
}

// ---------------- K2: bucket starts + per-(chunk,bucket) offsets (1 block) ----------------
__global__ __launch_bounds__(256) void scan_all(const int* __restrict__ bh,
                                                int* __restrict__ bstart,
                                                int* __restrict__ goff) {
    __shared__ int s[256];
    int b = threadIdx.x;
    int total = 0;
    if (b < NBUCK)
        for (int c = 0; c < NBUCK; ++c) total += bh[c * NBUCK + b];
    s[b] = total;
    __syncthreads();
#pragma unroll
    for (int off = 1; off < 256; off <<= 1) {
        int t = 0;
        if (b >= off) t = s[b - off];
        __syncthreads();
        if (b >= off) s[b] += t;
        __syncthreads();
    }
    int ex = s[b] - total;
    if (b < NBUCK) {
        bstart[b] = ex;
        int run = ex;
        for (int c = 0; c < NBUCK; ++c) {
            goff[c * NBUCK + b] = run;
            run += bh[c * NBUCK + b];
        }
    }
    if (b == 0) bstart[NBUCK] = N_EDGES;
}

// ---------------- K3: scatter (src,dst) pairs bucket-grouped — no global atomics ----------------
__global__ __launch_bounds__(256) void scatter_pairs(const int* __restrict__ src,
                                                     const int* __restrict__ dst,
                                                     const int* __restrict__ goff,
                                                     uint2* __restrict__ ebuf) {
    __shared__ int lgoff[NBUCK];
    __shared__ int lcur[NBUCK];
    int tid = threadIdx.x;
    int c = blockIdx.x;
    if (tid < NBUCK) {
        lgoff[tid] = goff[c * NBUCK + tid];
        lcur[tid] = 0;
    }
    __syncthreads();
    int e0 = c * CHUNK, e1 = min(e0 + CHUNK, N_EDGES);
    for (int e = e0 + tid; e < e1; e += 256) {
        int d = dst[e];
        int b = d >> 8;
        int slot = atomicAdd(&lcur[b], 1);
        ebuf[lgoff[b] + slot] = make_uint2((unsigned)src[e], (unsigned)d);
    }
}

// ---------------- K4: per-bucket count + scan + place; produces rowstart/cnt/dinv/esrc ----------------
__global__ __launch_bounds__(256) void bucket_sort(const uint2* __restrict__ ebuf,
                                                   const int* __restrict__ bstart,
                                                   int* __restrict__ rowstart,
                                                   int* __restrict__ cnt,
                                                   float* __restrict__ dinv,
                                                   int* __restrict__ esrc) {
    __shared__ int lcnt[256];
    __shared__ int ssc[256];
    __shared__ int ncur[256];
    int b = blockIdx.x, tid = threadIdx.x;
    int nbase = b * 256;
    int r0 = bstart[b], r1 = bstart[b + 1];
    lcnt[tid] = 0;
    __syncthreads();
    for (int i = r0 + tid; i < r1; i += 256)
        atomicAdd(&lcnt[(int)ebuf[i].y - nbase], 1);
    __syncthreads();
    int c = lcnt[tid];
    ssc[tid] = c;
    __syncthreads();
#pragma unroll
    for (int off = 1; off < 256; off <<= 1) {
        int t = 0;
        if (tid >= off) t = ssc[tid - off];
        __syncthreads();
        if (tid >= off) ssc[tid] += t;
        __syncthreads();
    }
    int rs = r0 + ssc[tid] - c;  // exclusive scan within bucket + bucket base
    ncur[tid] = rs;
    int node = nbase + tid;
    if (node < N_NODES) {
        rowstart[node] = rs;
        cnt[node] = c;
        dinv[node] = rsqrtf((float)c + 1.0f);
    }
    __syncthreads();
    for (int i = r0 + tid; i < r1; i += 256) {
        uint2 p = ebuf[i];
        int pos = atomicAdd(&ncur[(int)p.y - nbase], 1);
        esrc[pos] = (int)p.x;
    }
}

// ---------------- MFMA GEMM, layer 1: A is f32, converted in-register ----------------
__global__ __launch_bounds__(256) void gemm_mfma_f32A(const float* __restrict__ A,
                                                      const unsigned short* __restrict__ Wf,
                                                      const float* __restrict__ dinv,
                                                      unsigned short* __restrict__ hp) {
    const int KS = 3;  // K = 96
    const int wave = threadIdx.x >> 6;
    const int lane = threadIdx.x & 63;
    const int r0 = blockIdx.x * 64 + wave * 16;

    f32x4 acc[8];
#pragma unroll
    for (int t = 0; t < 8; ++t) acc[t] = (f32x4){0.f, 0.f, 0.f, 0.f};

    int arow = r0 + (lane & 15);
    if (arow >= N_NODES) arow = N_NODES - 1;  // clamp: padding rows discarded on store
    const int kq = (lane >> 4) * 8;

    for (int s = 0; s < KS; ++s) {
        const float* ap = A + (long)arow * F_IN + s * 32 + kq;
        float4 a0 = *(const float4*)(ap);
        float4 a1 = *(const float4*)(ap + 4);
        union { uint4 u; bf16x8 b; } af;
        af.u.x = (unsigned)f2bf(a0.x) | ((unsigned)f2bf(a0.y) << 16);
        af.u.y = (unsigned)f2bf(a0.z) | ((unsigned)f2bf(a0.w) << 16);
        af.u.z = (unsigned)f2bf(a1.x) | ((unsigned)f2bf(a1.y) << 16);
        af.u.w = (unsigned)f2bf(a1.z) | ((unsigned)f2bf(a1.w) << 16);
#pragma unroll
        for (int t = 0; t < 8; ++t) {
            union { uint4 u; bf16x8 b; } bfr;
            bfr.u = *(const uint4*)(Wf + ((long)(t * KS + s) * 64 + lane) * 8);
            acc[t] = __builtin_amdgcn_mfma_f32_16x16x32_bf16(af.b, bfr.b, acc[t], 0, 0, 0);
        }
    }

    const int q = lane >> 4;
    float dv[4];
#pragma unroll
    for (int r = 0; r < 4; ++r) {
        int row = r0 + q * 4 + r;
        dv[r] = dinv[row < N_NODES ? row : 0];
    }
#pragma unroll
    for (int t = 0; t < 8; ++t) {
        int col = t * 16 + (lane & 15);
#pragma unroll
        for (int r = 0; r < 4; ++r) {
            int row = r0 + q * 4 + r;
            if (row < N_NODES)
                hp[(long)row * 128 + col] = f2bf(acc[t][r] * dv[r]);
        }
    }
}

// ---------------- MFMA GEMM, layer 2: A is bf16 (h) ----------------
__global__ __launch_bounds__(256) void gemm_mfma_bf16A(const unsigned short* __restrict__ A,
                                                       const unsigned short* __restrict__ Wf,
                                                       const float* __restrict__ dinv,
                                                       unsigned short* __restrict__ hp) {
    const int KS = 4;  // K = 128
    const int wave = threadIdx.x >> 6;
    const int lane = threadIdx.x & 63;
    const int r0 = blockIdx.x * 64 + wave * 16;

    f32x4 acc[8];
#pragma unroll
    for (int t = 0; t < 8; ++t) acc[t] = (f32x4){0.f, 0.f, 0.f, 0.f};

    const int arow = r0 + (lane & 15);   // reads into ws padding are safe
    const int kq = (lane >> 4) * 8;

    for (int s = 0; s < KS; ++s) {
        union { uint4 u; bf16x8 b; } af;
        af.u = *(const uint4*)(A + (long)arow * HID + s * 32 + kq);
#pragma unroll
        for (int t = 0; t < 8; ++t) {
            union { uint4 u; bf16x8 b; } bfr;
            bfr.u = *(const uint4*)(Wf + ((long)(t * KS + s) * 64 + lane) * 8);
            acc[t] = __builtin_amdgcn_mfma_f32_16x16x32_bf16(af.b, bfr.b, acc[t], 0, 0, 0);
        }
    }

    const int q = lane >> 4;
    float dv[4];
#pragma unroll
    for (int r = 0; r < 4; ++r) {
        int row = r0 + q * 4 + r;
        dv[r] = dinv[row < N_NODES ? row : 0];
    }
#pragma unroll
    for (int t = 0; t < 8; ++t) {
        int col = t * 16 + (lane & 15);
#pragma unroll
        for (int r = 0; r < 4; ++r) {
            int row = r0 + q * 4 + r;
            if (row < N_NODES)
                hp[(long)row * 128 + col] = f2bf(acc[t][r] * dv[r]);
        }
    }
}

// ---------------- aggregate: 16 lanes x dwordx4, 4 loads in flight ----------------
__global__ __launch_bounds__(256) void aggregate4(const uint4* __restrict__ hp4,
                                                  const int* __restrict__ esrc,
                                                  const int* __restrict__ rowstart,
                                                  const int* __restrict__ cnt,
                                                  const float* __restrict__ dinv,
                                                  const float* __restrict__ bias,
                                                  uint4* __restrict__ hout4) {
    int node = blockIdx.x * 4 + (threadIdx.x >> 6);
    if (node >= N_NODES) return;
    int lane = threadIdx.x & 63;
    int eslot = lane >> 4;
    int ug = lane & 15;
    int start = rowstart[node];
    int end = start + cnt[node];

    float a[8];
#pragma unroll
    for (int k = 0; k < 8; ++k) a[k] = 0.f;

    for (int j = start; j < end; j += 16) {
        int e[4];
        uint4 v[4];
#pragma unroll
        for (int q = 0; q < 4; ++q) {
            e[q] = j + q * 4 + eslot;
            int s = esrc[min(e[q], end - 1)];
            v[q] = hp4[(long)s * 16 + ug];
        }
#pragma unroll
        for (int q = 0; q < 4; ++q) {
            if (e[q] < end) {
                a[0] += bflo(v[q].x); a[1] += bfhi(v[q].x);
                a[2] += bflo(v[q].y); a[3] += bfhi(v[q].y);
                a[4] += bflo(v[q].z); a[5] += bfhi(v[q].z);
                a[6] += bflo(v[q].w); a[7] += bfhi(v[q].w);
            }
        }
    }

#pragma unroll
    for (int k = 0; k < 8; ++k) {
        a[k] += __shfl_xor(a[k], 16);
        a[k] += __shfl_xor(a[k], 32);
    }

    if (eslot == 0) {
        uint4 vs = hp4[(long)node * 16 + ug];
        a[0] += bflo(vs.x); a[1] += bfhi(vs.x);
        a[2] += bflo(vs.y); a[3] += bfhi(vs.y);
        a[4] += bflo(vs.z); a[5] += bfhi(vs.z);
        a[6] += bflo(vs.w); a[7] += bfhi(vs.w);
        float d = dinv[node];
        float4 b0 = *(const float4*)(bias + ug * 8);
        float4 b1 = *(const float4*)(bias + ug * 8 + 4);
        float o0 = fmaxf(d * a[0] + b0.x, 0.f), o1 = fmaxf(d * a[1] + b0.y, 0.f);
        float o2 = fmaxf(d * a[2] + b0.z, 0.f), o3 = fmaxf(d * a[3] + b0.w, 0.f);
        float o4 = fmaxf(d * a[4] + b1.x, 0.f), o5 = fmaxf(d * a[5] + b1.y, 0.f);
        float o6 = fmaxf(d * a[6] + b1.z, 0.f), o7 = fmaxf(d * a[7] + b1.w, 0.f);
        uint4 o;
        o.x = (unsigned)f2bf(o0) | ((unsigned)f2bf(o1) << 16);
        o.y = (unsigned)f2bf(o2) | ((unsigned)f2bf(o3) << 16);
        o.z = (unsigned)f2bf(o4) | ((unsigned)f2bf(o5) << 16);
        o.w = (unsigned)f2bf(o6) | ((unsigned)f2bf(o7) << 16);
        hout4[(long)node * 16 + ug] = o;
    }
}

// ---------------- pooling + head ----------------

__global__ __launch_bounds__(128) void pool_head(const unsigned short* __restrict__ h,
                                                 const int* __restrict__ batch,
                                                 const float* __restrict__ Wlin,
                                                 const float* __restrict__ blin,
                                                 float* __restrict__ out) {
    __shared__ int bnd[2];
    int g = blockIdx.x;
    int c = threadIdx.x;
    if (c < 2) {
        int target = g + c;
        int lo = 0, hi = N_NODES;
        while (lo < hi) {
            int mid = (lo + hi) >> 1;
            if (batch[mid] < target) lo = mid + 1;
            else hi = mid;
        }
        bnd[c] = lo;
    }
    __syncthreads();
    int s = bnd[0], e = bnd[1];

    float sum = 0.f;
    for (int i = s; i < e; ++i) {
        union { unsigned u; float f; } v;
        v.u = (unsigned)h[(long)i * 128 + c] << 16;
        sum += v.f;
    }
    float inv = (e > s) ? 1.0f / (float)(e - s) : 1.0f;
    float m = sum * inv;

    __shared__ float red[128][2];
    red[c][0] = m * Wlin[c * 2 + 0];
    red[c][1] = m * Wlin[c * 2 + 1];
    __syncthreads();
#pragma unroll
    for (int off = 64; off > 0; off >>= 1) {
        if (c < off) {
            red[c][0] += red[c + off][0];
            red[c][1] += red[c + off][1];
        }
        __syncthreads();
    }
    if (c < 2) out[g * 2 + c] = red[0][c] + blin[c];
}

extern "C" void kernel_launch(void* const* d_in, const int* in_sizes, int n_in,
                              void* d_out, int out_size, void* d_ws, size_t ws_size,
                              hipStream_t stream) {
    const float* x    = (const float*)d_in[0];
    const int*   ei   = (const int*)d_in[1];
    const int*   batch= (const int*)d_in[2];
    const float* W1   = (const float*)d_in[4];
    const float* b1   = (const float*)d_in[5];
    const float* W2   = (const float*)d_in[6];
    const float* b2   = (const float*)d_in[7];
    const float* Wlin = (const float*)d_in[8];
    const float* blin = (const float*)d_in[9];
    float* out = (float*)d_out;

    const int* src = ei;
    const int* dst = ei + N_EDGES;

    char* ws = (char*)d_ws;
    const size_t KB = 1024;
    const size_t MB = 1024 * 1024;

    float* dinv     = (float*)(ws);                      // 200 KB
    int*   cnt      = (int*)  (ws + 256 * KB);           // 200 KB
    int*   rowstart = (int*)  (ws + 512 * KB);           // 200 KB
    int*   bstart   = (int*)  (ws + 768 * KB);           // 788 B
    int*   bh       = (int*)  (ws + 832 * KB);           // 154 KB
    int*   goff     = (int*)  (ws + 1 * MB);             // 154 KB
    uint2* ebuf     = (uint2*)(ws + 2 * MB);             // 6.4 MB
    int*   esrc     = (int*)  (ws + 9 * MB);             // 3.2 MB
    unsigned short* W1f = (unsigned short*)(ws + 12 * MB + 512 * KB);  // 24 KB
    unsigned short* W2f = (unsigned short*)(ws + 12 * MB + 576 * KB);  // 32 KB
    unsigned short* hp  = (unsigned short*)(ws + 13 * MB);             // 12.82 MB (N_PAD rows)
    unsigned short* h   = (unsigned short*)(ws + 26 * MB);             // 12.82 MB

    const int NB_G  = N_PAD / 64;                         // 782
    const int NB_AG = (N_NODES + 3) / 4;                  // 12500

    // ---- CSR build (atomic-free at global scope; reused by both layers) ----
    bucket_hist<<<NBUCK + 14, 256, 0, stream>>>(dst, W1, W2, W1f, W2f, bh);
    scan_all<<<1, 256, 0, stream>>>(bh, bstart, goff);
    scatter_pairs<<<NBUCK, 256, 0, stream>>>(src, dst, goff, ebuf);
    bucket_sort<<<NBUCK, 256, 0, stream>>>(ebuf, bstart, rowstart, cnt, dinv, esrc);

    // ---- layer 1 ----
    gemm_mfma_f32A<<<NB_G, 256, 0, stream>>>(x, W1f, dinv, hp);
    aggregate4<<<NB_AG, 256, 0, stream>>>((const uint4*)hp, esrc, rowstart, cnt, dinv, b1, (uint4*)h);

    // ---- layer 2 ----
    gemm_mfma_bf16A<<<NB_G, 256, 0, stream>>>(h, W2f, dinv, hp);
    aggregate4<<<NB_AG, 256, 0, stream>>>((const uint4*)hp, esrc, rowstart, cnt, dinv, b2, (uint4*)h);

    // ---- pooling + head ----
    pool_head<<<N_GRAPHS, 128, 0, stream>>>(h, batch, Wlin, blin, out);
}